// Round 7
// baseline (1096.322 us; speedup 1.0000x reference)
//
#include <hip/hip_runtime.h>

// ---------------------------------------------------------------------------
// GNN: 3x GraphConv (norm='both') + avg-pool + MLP(128->512->256->1), fp32.
// R7: XCD-sliced gather. csr_agg splits each 128-float row into 8 slices of
// 16 floats (one 64B line); blockIdx&7 = slice ~ XCD id under round-robin
// dispatch -> per-XCD working set 51MB -> 6.4MB (~L2), cutting the 8x
// cross-XCD refetch seen as FETCH_SIZE ~= 8*|hs| in R6. Correct for any
// block->XCD mapping. Rest identical to R6 (best: 815us).
// ---------------------------------------------------------------------------

static inline int ceil_div(int a, int b){ return (a + b - 1) / b; }

#define B1 128          // pass-1 blocks
#define NBMAX 1024      // max buckets (N <= 131072; src ids fit in 17 bits)

// Pass 1a: per-block bucket counts for dst (job A) and src (job B).
__global__ __launch_bounds__(256) void bucket_count_kernel(
    const int* __restrict__ src, const int* __restrict__ dst,
    unsigned* __restrict__ cntA, unsigned* __restrict__ cntB,
    int E, int NB){
  __shared__ unsigned la[NBMAX], lb[NBMAX];
  int t = threadIdx.x;
  for (int i = t; i < NB; i += 256){ la[i] = 0u; lb[i] = 0u; }
  __syncthreads();
  int chunk = (E + B1 - 1) / B1;
  int e0 = blockIdx.x * chunk, e1 = min(e0 + chunk, E);
  for (int e = e0 + t; e < e1; e += 256){
    atomicAdd(&la[dst[e] >> 7], 1u);
    atomicAdd(&lb[src[e] >> 7], 1u);
  }
  __syncthreads();
  for (int i = t; i < NB; i += 256){
    cntA[(size_t)blockIdx.x * NB + i] = la[i];
    cntB[(size_t)blockIdx.x * NB + i] = lb[i];
  }
}

// Column-wise exclusive scan over blocks for each bucket; emits totals.
__global__ void scan_cols_kernel(unsigned* __restrict__ cntA, unsigned* __restrict__ cntB,
                                 unsigned* __restrict__ totals, int NB){
  int b = blockIdx.x * 256 + threadIdx.x;
  if (b >= NB) return;
  unsigned* cnt = blockIdx.y ? cntB : cntA;
  unsigned run = 0;
  for (int blk = 0; blk < B1; blk++){
    unsigned v = cnt[(size_t)blk * NB + b];
    cnt[(size_t)blk * NB + b] = run;
    run += v;
  }
  totals[(size_t)blockIdx.y * NB + b] = run;
}

// Single-block exclusive scan of bucket totals -> baseA/baseB (each NB+1).
__global__ void scan_base_kernel(const unsigned* __restrict__ totals,
                                 unsigned* __restrict__ baseA, unsigned* __restrict__ baseB,
                                 int NB, int E){
  __shared__ unsigned s[NBMAX];
  int t = threadIdx.x;  // 1024 threads, NB <= 1024
  for (int job = 0; job < 2; job++){
    unsigned* base = job ? baseB : baseA;
    unsigned x = (t < NB) ? totals[(size_t)job * NB + t] : 0u;
    s[t] = x;
    __syncthreads();
    for (int off = 1; off < NBMAX; off <<= 1){
      unsigned v = (t >= off) ? s[t - off] : 0u;
      __syncthreads();
      s[t] += v;
      __syncthreads();
    }
    if (t < NB) base[t] = s[t] - x;
    if (t == 0) base[NB] = (unsigned)E;
    __syncthreads();
  }
}

// Pass 1b: scatter edges into bucketed arrays using per-block reserved offsets.
// A-job entry: ((dst&127)<<17) | src   (one u32 instead of two ints)
// B-job entry: src&127 as u8.
__global__ __launch_bounds__(256) void bucket_scatter_kernel(
    const int* __restrict__ src, const int* __restrict__ dst,
    const unsigned* __restrict__ cntA, const unsigned* __restrict__ cntB,
    const unsigned* __restrict__ baseA, const unsigned* __restrict__ baseB,
    unsigned* __restrict__ bpack_d, unsigned char* __restrict__ bsrc_s,
    int E, int NB){
  __shared__ unsigned curA[NBMAX], curB[NBMAX];
  int t = threadIdx.x;
  for (int i = t; i < NB; i += 256){
    curA[i] = baseA[i] + cntA[(size_t)blockIdx.x * NB + i];
    curB[i] = baseB[i] + cntB[(size_t)blockIdx.x * NB + i];
  }
  __syncthreads();
  int chunk = (E + B1 - 1) / B1;
  int e0 = blockIdx.x * chunk, e1 = min(e0 + chunk, E);
  for (int e = e0 + t; e < e1; e += 256){
    int s = src[e], d = dst[e];
    unsigned p = atomicAdd(&curA[d >> 7], 1u);
    bpack_d[p] = ((unsigned)(d & 127) << 17) | (unsigned)s;
    unsigned q = atomicAdd(&curB[s >> 7], 1u);
    bsrc_s[q] = (unsigned char)(s & 127);
  }
}

// Pass 2a: per-bucket CSR finalize: row_ptr, inv_dst, col (contiguous range).
__global__ __launch_bounds__(256) void csr_finalize_kernel(
    const unsigned* __restrict__ bpack_d, const unsigned* __restrict__ baseA,
    int* __restrict__ row_ptr, float* __restrict__ inv_dst, int* __restrict__ col,
    int N, int E, int NB){
  __shared__ unsigned cnt[128];
  __shared__ unsigned scn[128];
  int b = blockIdx.x, t = threadIdx.x;
  int node0 = b << 7;
  int nn = min(128, N - node0);
  int e0 = (int)baseA[b], e1 = (int)baseA[b + 1];
  if (t < 128) cnt[t] = 0u;
  __syncthreads();
  for (int e = e0 + t; e < e1; e += 256)
    atomicAdd(&cnt[(bpack_d[e] >> 17) & 127u], 1u);
  __syncthreads();
  unsigned mycnt = (t < 128) ? cnt[t] : 0u;
  if (t < 128) scn[t] = mycnt;
  __syncthreads();
  for (int off = 1; off < 128; off <<= 1){
    unsigned v = (t < 128 && t >= off) ? scn[t - off] : 0u;
    __syncthreads();
    if (t < 128) scn[t] += v;
    __syncthreads();
  }
  if (t < nn){
    unsigned excl = scn[t] - mycnt;
    row_ptr[node0 + t] = e0 + (int)excl;
    unsigned c = mycnt < 1u ? 1u : mycnt;
    inv_dst[node0 + t] = rsqrtf((float)c);
    cnt[t] = (unsigned)e0 + excl;   // reuse as cursor
  }
  if (b == NB - 1 && t == 0) row_ptr[N] = E;
  __syncthreads();
  for (int e = e0 + t; e < e1; e += 256){
    unsigned v = bpack_d[e];
    unsigned p = atomicAdd(&cnt[(v >> 17) & 127u], 1u);
    col[p] = (int)(v & 0x1FFFFu);
  }
}

// Pass 2b: per-bucket out-degree -> inv_src.
__global__ __launch_bounds__(256) void degout_finalize_kernel(
    const unsigned char* __restrict__ bsrc_s, const unsigned* __restrict__ baseB,
    float* __restrict__ inv_src, int N){
  __shared__ unsigned cnt[128];
  int b = blockIdx.x, t = threadIdx.x;
  int node0 = b << 7;
  int nn = min(128, N - node0);
  int e0 = (int)baseB[b], e1 = (int)baseB[b + 1];
  if (t < 128) cnt[t] = 0u;
  __syncthreads();
  for (int e = e0 + t; e < e1; e += 256)
    atomicAdd(&cnt[bsrc_s[e]], 1u);
  __syncthreads();
  if (t < nn){
    unsigned c = cnt[t] < 1u ? 1u : cnt[t];
    inv_src[node0 + t] = rsqrtf((float)c);
  }
}

// hs = feats * inv_src (row scale), float4 vectorized
__global__ void scale_rows_kernel(const float* __restrict__ in, const float* __restrict__ sc,
                                  float* __restrict__ out, int n4){
  int i = blockIdx.x*blockDim.x + threadIdx.x;
  if (i < n4){
    float4 v = ((const float4*)in)[i];
    float s = sc[i >> 5];            // 32 float4 per 128-wide row
    v.x *= s; v.y *= s; v.z *= s; v.w *= s;
    ((float4*)out)[i] = v;
  }
}

// XCD-sliced gather: blockIdx&7 = feature slice (16 floats = one 64B line);
// block covers 64 nodes for its slice; 4 lanes (float4 each) per node.
// Edge-order accumulation tree identical to R6 (unroll 4, pairwise merge).
__global__ __launch_bounds__(256) void csr_agg_kernel(
    const int* __restrict__ row_ptr, const int* __restrict__ col,
    const float* __restrict__ hs, float* __restrict__ agg, int N){
  const int slice = blockIdx.x & 7;
  const int nbase = (int)(blockIdx.x >> 3) * 64;
  const int wave  = threadIdx.x >> 6;
  const int lane  = threadIdx.x & 63;
  const int group = lane >> 2;       // node within wave: 0..15
  const int sub   = lane & 3;        // float4 slot within 16-float slice
  const int node  = nbase + wave*16 + group;
  if (node >= N) return;
  const float* base = hs + (size_t)slice*16 + (size_t)sub*4;
  int r0 = row_ptr[node];
  int r1 = row_ptr[node+1];
  float4 a0 = make_float4(0.f,0.f,0.f,0.f);
  float4 a1 = make_float4(0.f,0.f,0.f,0.f);
  float4 a2 = make_float4(0.f,0.f,0.f,0.f);
  float4 a3 = make_float4(0.f,0.f,0.f,0.f);
  int e = r0;
  for (; e + 3 < r1; e += 4){
    int s0 = col[e], s1 = col[e+1], s2 = col[e+2], s3 = col[e+3];
    float4 v0 = *(const float4*)(base + (size_t)s0*128);
    float4 v1 = *(const float4*)(base + (size_t)s1*128);
    float4 v2 = *(const float4*)(base + (size_t)s2*128);
    float4 v3 = *(const float4*)(base + (size_t)s3*128);
    a0.x += v0.x; a0.y += v0.y; a0.z += v0.z; a0.w += v0.w;
    a1.x += v1.x; a1.y += v1.y; a1.z += v1.z; a1.w += v1.w;
    a2.x += v2.x; a2.y += v2.y; a2.z += v2.z; a2.w += v2.w;
    a3.x += v3.x; a3.y += v3.y; a3.z += v3.z; a3.w += v3.w;
  }
  for (; e < r1; e++){
    int s0 = col[e];
    float4 v0 = *(const float4*)(base + (size_t)s0*128);
    a0.x += v0.x; a0.y += v0.y; a0.z += v0.z; a0.w += v0.w;
  }
  float4 r;
  r.x = (a0.x + a1.x) + (a2.x + a3.x);
  r.y = (a0.y + a1.y) + (a2.y + a3.y);
  r.z = (a0.z + a1.z) + (a2.z + a3.z);
  r.w = (a0.w + a1.w) + (a2.w + a3.w);
  *(float4*)(agg + (size_t)node*128 + slice*16 + sub*4) = r;
}

// Tiled fp32 SGEMM: out[M x Ncols] = act( (A .* row_scale) @ W + bias ) .* out_scale
__global__ __launch_bounds__(256) void gemm_kernel(
    const float* __restrict__ A, const float* __restrict__ W,
    const float* __restrict__ bias, const float* __restrict__ row_scale,
    const float* __restrict__ out_scale, float* __restrict__ out,
    int M, int K, int Ncols, int do_relu){
  __shared__ float As[32][68];
  __shared__ float Bs[32][128];

  const int tid = threadIdx.x;
  const int tx = tid & 31;
  const int ty = tid >> 5;
  const int row0 = blockIdx.x * 64;
  const int col0 = blockIdx.y * 128;

  float acc[8][4];
  #pragma unroll
  for (int i = 0; i < 8; i++)
    #pragma unroll
    for (int j = 0; j < 4; j++) acc[i][j] = 0.f;

  for (int kb = 0; kb < K; kb += 32){
    #pragma unroll
    for (int i = 0; i < 2; i++){
      int flat = i*256 + tid;
      int m = flat >> 3, k4 = (flat & 7) << 2;
      int gm = row0 + m;
      float4 v = make_float4(0.f, 0.f, 0.f, 0.f);
      if (gm < M){
        v = *(const float4*)(A + (size_t)gm*K + kb + k4);
        if (row_scale){ float s = row_scale[gm]; v.x*=s; v.y*=s; v.z*=s; v.w*=s; }
      }
      As[k4+0][m] = v.x; As[k4+1][m] = v.y; As[k4+2][m] = v.z; As[k4+3][m] = v.w;
    }
    #pragma unroll
    for (int i = 0; i < 4; i++){
      int flat = i*256 + tid;
      int k = flat >> 5, j4 = (flat & 31) << 2;
      float4 v = *(const float4*)(W + (size_t)(kb + k)*Ncols + col0 + j4);
      *(float4*)&Bs[k][j4] = v;
    }
    __syncthreads();
    #pragma unroll
    for (int k = 0; k < 32; k++){
      float4 b = *(const float4*)&Bs[k][tx << 2];
      float a[8];
      #pragma unroll
      for (int i = 0; i < 8; i++) a[i] = As[k][ty*8 + i];
      #pragma unroll
      for (int i = 0; i < 8; i++){
        acc[i][0] = fmaf(a[i], b.x, acc[i][0]);
        acc[i][1] = fmaf(a[i], b.y, acc[i][1]);
        acc[i][2] = fmaf(a[i], b.z, acc[i][2]);
        acc[i][3] = fmaf(a[i], b.w, acc[i][3]);
      }
    }
    __syncthreads();
  }

  float4 bi = *(const float4*)(bias + col0 + (tx << 2));
  #pragma unroll
  for (int i = 0; i < 8; i++){
    int gm = row0 + ty*8 + i;
    if (gm < M){
      float4 v;
      v.x = acc[i][0] + bi.x; v.y = acc[i][1] + bi.y;
      v.z = acc[i][2] + bi.z; v.w = acc[i][3] + bi.w;
      if (do_relu){
        v.x = fmaxf(v.x, 0.f); v.y = fmaxf(v.y, 0.f);
        v.z = fmaxf(v.z, 0.f); v.w = fmaxf(v.w, 0.f);
      }
      if (out_scale){ float s = out_scale[gm]; v.x*=s; v.y*=s; v.z*=s; v.w*=s; }
      *(float4*)(out + (size_t)gm*Ncols + col0 + (tx << 2)) = v;
    }
  }
}

// Avg-pool per graph: graph_ids sorted -> binary search bounds, wave per graph.
__global__ void pool_kernel(const float* __restrict__ h, const int* __restrict__ gid,
                            float* __restrict__ emb, int N, int G){
  int g = blockIdx.x;
  int lane = threadIdx.x;   // 64 threads
  int lo = 0, hi = N;
  while (lo < hi){ int mid = (lo + hi) >> 1; if (gid[mid] < g) lo = mid + 1; else hi = mid; }
  int start = lo;
  hi = N;
  while (lo < hi){ int mid = (lo + hi) >> 1; if (gid[mid] <= g) lo = mid + 1; else hi = mid; }
  int end = lo;
  float ax = 0.f, ay = 0.f;
  for (int n = start; n < end; n++){
    float2 v = ((const float2*)(h + (size_t)n*128))[lane];
    ax += v.x; ay += v.y;
  }
  int c = end - start; if (c < 1) c = 1;
  float invc = 1.0f / (float)c;
  float2 r; r.x = ax * invc; r.y = ay * invc;
  ((float2*)(emb + (size_t)g*128))[lane] = r;
}

// Final 256->1: wave per graph, float4 per lane, shuffle reduce.
__global__ void final_dot_kernel(const float* __restrict__ x, const float* __restrict__ w,
                                 const float* __restrict__ b, float* __restrict__ out, int G){
  int idx = blockIdx.x*blockDim.x + threadIdx.x;
  int g = idx >> 6, lane = idx & 63;
  if (g >= G) return;
  float4 xv = ((const float4*)(x + (size_t)g*256))[lane];
  float4 wv = ((const float4*)w)[lane];
  float s = xv.x*wv.x + xv.y*wv.y + xv.z*wv.z + xv.w*wv.w;
  for (int off = 32; off > 0; off >>= 1) s += __shfl_down(s, off);
  if (lane == 0) out[g] = s + b[0];
}

extern "C" void kernel_launch(void* const* d_in, const int* in_sizes, int n_in,
                              void* d_out, int out_size, void* d_ws, size_t ws_size,
                              hipStream_t stream){
  const float* feats = (const float*)d_in[0];
  const int*   src   = (const int*)d_in[1];
  const int*   dst   = (const int*)d_in[2];
  const int*   gid   = (const int*)d_in[3];
  const float* W0 = (const float*)d_in[4];   const float* b0 = (const float*)d_in[5];
  const float* W1 = (const float*)d_in[6];   const float* b1 = (const float*)d_in[7];
  const float* W2 = (const float*)d_in[8];   const float* b2 = (const float*)d_in[9];
  const float* Wm0 = (const float*)d_in[10]; const float* bm0 = (const float*)d_in[11];
  const float* Wm1 = (const float*)d_in[12]; const float* bm1 = (const float*)d_in[13];
  const float* Wm2 = (const float*)d_in[14]; const float* bm2 = (const float*)d_in[15];
  float* out = (float*)d_out;

  const int E   = in_sizes[1];
  const int N   = in_sizes[3];
  const int G   = out_size;
  const int MH  = in_sizes[11];   // 512
  const int MH2 = in_sizes[13];   // 256
  const int NB  = ceil_div(N, 128);   // 782 for N=100000 (<= NBMAX)

  char* ws = (char*)d_ws;
  size_t off = 0;
  auto carve = [&](size_t bytes) -> char* {
    off = (off + 255) & ~(size_t)255;
    char* p = ws + off; off += bytes; return p;
  };
  float* inv_src = (float*)carve((size_t)N*4);
  float* inv_dst = (float*)carve((size_t)N*4);
  int* row_ptr = (int*)carve((size_t)(N+1)*4);
  int* col     = (int*)carve((size_t)E*4);
  float* hs  = (float*)carve((size_t)N*128*4);
  float* agg = (float*)carve((size_t)N*128*4);
  float* emb = (float*)carve((size_t)G*128*4);
  float* x1  = (float*)carve((size_t)G*MH*4);
  float* x2  = (float*)carve((size_t)G*MH2*4);

  // CSR-build temporaries alias agg (dead until first csr_agg writes it).
  unsigned* T = (unsigned*)agg;
  unsigned* cntA   = T;
  unsigned* cntB   = cntA + (size_t)B1*NB;
  unsigned* totals = cntB + (size_t)B1*NB;
  unsigned* baseA  = totals + 2*(size_t)NB;
  unsigned* baseB  = baseA + (NB+1);
  unsigned* bpack_d = baseB + (NB+1);
  unsigned char* bsrc_s = (unsigned char*)(bpack_d + E);

  bucket_count_kernel<<<B1, 256, 0, stream>>>(src, dst, cntA, cntB, E, NB);
  scan_cols_kernel<<<dim3(ceil_div(NB,256), 2), 256, 0, stream>>>(cntA, cntB, totals, NB);
  scan_base_kernel<<<1, NBMAX, 0, stream>>>(totals, baseA, baseB, NB, E);
  bucket_scatter_kernel<<<B1, 256, 0, stream>>>(src, dst, cntA, cntB, baseA, baseB,
                                                bpack_d, bsrc_s, E, NB);
  csr_finalize_kernel<<<NB, 256, 0, stream>>>(bpack_d, baseA, row_ptr, inv_dst, col, N, E, NB);
  degout_finalize_kernel<<<NB, 256, 0, stream>>>(bsrc_s, baseB, inv_src, N);
  scale_rows_kernel<<<ceil_div(N*32,256), 256, 0, stream>>>(feats, inv_src, hs, N*32);

  const int agg_blocks = ceil_div(N, 64) * 8;   // x8 slices, blockIdx&7 = slice
  dim3 ggrid(ceil_div(N,64), 1);
  // layer 0: agg = CSR-sum(hs); hs = relu(agg*inv_dst @ W0 + b0) * inv_src
  csr_agg_kernel<<<agg_blocks, 256, 0, stream>>>(row_ptr, col, hs, agg, N);
  gemm_kernel<<<ggrid, 256, 0, stream>>>(agg, W0, b0, inv_dst, inv_src, hs, N, 128, 128, 1);
  // layer 1
  csr_agg_kernel<<<agg_blocks, 256, 0, stream>>>(row_ptr, col, hs, agg, N);
  gemm_kernel<<<ggrid, 256, 0, stream>>>(agg, W1, b1, inv_dst, inv_src, hs, N, 128, 128, 1);
  // layer 2 (no out_scale: plain h3 for pooling)
  csr_agg_kernel<<<agg_blocks, 256, 0, stream>>>(row_ptr, col, hs, agg, N);
  gemm_kernel<<<ggrid, 256, 0, stream>>>(agg, W2, b2, inv_dst, nullptr, hs, N, 128, 128, 1);
  // avg pooling
  pool_kernel<<<G, 64, 0, stream>>>(hs, gid, emb, N, G);
  // MLP head
  gemm_kernel<<<dim3(ceil_div(G,64), MH/128),  256, 0, stream>>>(emb, Wm0, bm0, nullptr, nullptr, x1, G, 128, MH, 1);
  gemm_kernel<<<dim3(ceil_div(G,64), MH2/128), 256, 0, stream>>>(x1, Wm1, bm1, nullptr, nullptr, x2, G, MH, MH2, 1);
  final_dot_kernel<<<ceil_div(G*64,256), 256, 0, stream>>>(x2, Wm2, bm2, out, G);
}

// Round 8
// 804.575 us; speedup vs baseline: 1.3626x; 1.3626x over previous
//
#include <hip/hip_runtime.h>

// ---------------------------------------------------------------------------
// GNN: 3x GraphConv (norm='both') + avg-pool + MLP(128->512->256->1), fp32.
// R8: R6 base (best, 815us) + layer GEMMs moved to split-bf16 MFMA
// (hi/lo decomposition, 3 mfma_f32_16x16x32_bf16 per tile: hh+hl+lh;
// lo*lo dropped ~2^-18 rel). W prepped once/layer into bf16 Whi/Wlo [n][k].
// csr_agg reverted to R6 shape (R7 slicing doubled FETCH: 128B granularity
// + no XCD mapping control -> csr_agg is at its structural roofline).
// ---------------------------------------------------------------------------

static inline int ceil_div(int a, int b){ return (a + b - 1) / b; }

#define B1 128          // pass-1 blocks
#define NBMAX 1024      // max buckets (N <= 131072; src ids fit in 17 bits)

typedef __bf16 bf16x8 __attribute__((ext_vector_type(8)));
typedef float  f32x4  __attribute__((ext_vector_type(4)));

// Pass 1a: per-block bucket counts for dst (job A) and src (job B).
__global__ __launch_bounds__(256) void bucket_count_kernel(
    const int* __restrict__ src, const int* __restrict__ dst,
    unsigned* __restrict__ cntA, unsigned* __restrict__ cntB,
    int E, int NB){
  __shared__ unsigned la[NBMAX], lb[NBMAX];
  int t = threadIdx.x;
  for (int i = t; i < NB; i += 256){ la[i] = 0u; lb[i] = 0u; }
  __syncthreads();
  int chunk = (E + B1 - 1) / B1;
  int e0 = blockIdx.x * chunk, e1 = min(e0 + chunk, E);
  for (int e = e0 + t; e < e1; e += 256){
    atomicAdd(&la[dst[e] >> 7], 1u);
    atomicAdd(&lb[src[e] >> 7], 1u);
  }
  __syncthreads();
  for (int i = t; i < NB; i += 256){
    cntA[(size_t)blockIdx.x * NB + i] = la[i];
    cntB[(size_t)blockIdx.x * NB + i] = lb[i];
  }
}

// Column-wise exclusive scan over blocks for each bucket; emits totals.
__global__ void scan_cols_kernel(unsigned* __restrict__ cntA, unsigned* __restrict__ cntB,
                                 unsigned* __restrict__ totals, int NB){
  int b = blockIdx.x * 256 + threadIdx.x;
  if (b >= NB) return;
  unsigned* cnt = blockIdx.y ? cntB : cntA;
  unsigned run = 0;
  for (int blk = 0; blk < B1; blk++){
    unsigned v = cnt[(size_t)blk * NB + b];
    cnt[(size_t)blk * NB + b] = run;
    run += v;
  }
  totals[(size_t)blockIdx.y * NB + b] = run;
}

// Single-block exclusive scan of bucket totals -> baseA/baseB (each NB+1).
__global__ void scan_base_kernel(const unsigned* __restrict__ totals,
                                 unsigned* __restrict__ baseA, unsigned* __restrict__ baseB,
                                 int NB, int E){
  __shared__ unsigned s[NBMAX];
  int t = threadIdx.x;  // 1024 threads, NB <= 1024
  for (int job = 0; job < 2; job++){
    unsigned* base = job ? baseB : baseA;
    unsigned x = (t < NB) ? totals[(size_t)job * NB + t] : 0u;
    s[t] = x;
    __syncthreads();
    for (int off = 1; off < NBMAX; off <<= 1){
      unsigned v = (t >= off) ? s[t - off] : 0u;
      __syncthreads();
      s[t] += v;
      __syncthreads();
    }
    if (t < NB) base[t] = s[t] - x;
    if (t == 0) base[NB] = (unsigned)E;
    __syncthreads();
  }
}

// Pass 1b: scatter edges into bucketed arrays using per-block reserved offsets.
__global__ __launch_bounds__(256) void bucket_scatter_kernel(
    const int* __restrict__ src, const int* __restrict__ dst,
    const unsigned* __restrict__ cntA, const unsigned* __restrict__ cntB,
    const unsigned* __restrict__ baseA, const unsigned* __restrict__ baseB,
    unsigned* __restrict__ bpack_d, unsigned char* __restrict__ bsrc_s,
    int E, int NB){
  __shared__ unsigned curA[NBMAX], curB[NBMAX];
  int t = threadIdx.x;
  for (int i = t; i < NB; i += 256){
    curA[i] = baseA[i] + cntA[(size_t)blockIdx.x * NB + i];
    curB[i] = baseB[i] + cntB[(size_t)blockIdx.x * NB + i];
  }
  __syncthreads();
  int chunk = (E + B1 - 1) / B1;
  int e0 = blockIdx.x * chunk, e1 = min(e0 + chunk, E);
  for (int e = e0 + t; e < e1; e += 256){
    int s = src[e], d = dst[e];
    unsigned p = atomicAdd(&curA[d >> 7], 1u);
    bpack_d[p] = ((unsigned)(d & 127) << 17) | (unsigned)s;
    unsigned q = atomicAdd(&curB[s >> 7], 1u);
    bsrc_s[q] = (unsigned char)(s & 127);
  }
}

// Pass 2a: per-bucket CSR finalize: row_ptr, inv_dst, col (contiguous range).
__global__ __launch_bounds__(256) void csr_finalize_kernel(
    const unsigned* __restrict__ bpack_d, const unsigned* __restrict__ baseA,
    int* __restrict__ row_ptr, float* __restrict__ inv_dst, int* __restrict__ col,
    int N, int E, int NB){
  __shared__ unsigned cnt[128];
  __shared__ unsigned scn[128];
  int b = blockIdx.x, t = threadIdx.x;
  int node0 = b << 7;
  int nn = min(128, N - node0);
  int e0 = (int)baseA[b], e1 = (int)baseA[b + 1];
  if (t < 128) cnt[t] = 0u;
  __syncthreads();
  for (int e = e0 + t; e < e1; e += 256)
    atomicAdd(&cnt[(bpack_d[e] >> 17) & 127u], 1u);
  __syncthreads();
  unsigned mycnt = (t < 128) ? cnt[t] : 0u;
  if (t < 128) scn[t] = mycnt;
  __syncthreads();
  for (int off = 1; off < 128; off <<= 1){
    unsigned v = (t < 128 && t >= off) ? scn[t - off] : 0u;
    __syncthreads();
    if (t < 128) scn[t] += v;
    __syncthreads();
  }
  if (t < nn){
    unsigned excl = scn[t] - mycnt;
    row_ptr[node0 + t] = e0 + (int)excl;
    unsigned c = mycnt < 1u ? 1u : mycnt;
    inv_dst[node0 + t] = rsqrtf((float)c);
    cnt[t] = (unsigned)e0 + excl;   // reuse as cursor
  }
  if (b == NB - 1 && t == 0) row_ptr[N] = E;
  __syncthreads();
  for (int e = e0 + t; e < e1; e += 256){
    unsigned v = bpack_d[e];
    unsigned p = atomicAdd(&cnt[(v >> 17) & 127u], 1u);
    col[p] = (int)(v & 0x1FFFFu);
  }
}

// Pass 2b: per-bucket out-degree -> inv_src.
__global__ __launch_bounds__(256) void degout_finalize_kernel(
    const unsigned char* __restrict__ bsrc_s, const unsigned* __restrict__ baseB,
    float* __restrict__ inv_src, int N){
  __shared__ unsigned cnt[128];
  int b = blockIdx.x, t = threadIdx.x;
  int node0 = b << 7;
  int nn = min(128, N - node0);
  int e0 = (int)baseB[b], e1 = (int)baseB[b + 1];
  if (t < 128) cnt[t] = 0u;
  __syncthreads();
  for (int e = e0 + t; e < e1; e += 256)
    atomicAdd(&cnt[bsrc_s[e]], 1u);
  __syncthreads();
  if (t < nn){
    unsigned c = cnt[t] < 1u ? 1u : cnt[t];
    inv_src[node0 + t] = rsqrtf((float)c);
  }
}

// hs = feats * inv_src (row scale), float4 vectorized
__global__ void scale_rows_kernel(const float* __restrict__ in, const float* __restrict__ sc,
                                  float* __restrict__ out, int n4){
  int i = blockIdx.x*blockDim.x + threadIdx.x;
  if (i < n4){
    float4 v = ((const float4*)in)[i];
    float s = sc[i >> 5];            // 32 float4 per 128-wide row
    v.x *= s; v.y *= s; v.z *= s; v.w *= s;
    ((float4*)out)[i] = v;
  }
}

// Half-wave (32 lanes) per node; lane owns a float4. (R6 best variant.)
__global__ __launch_bounds__(256) void csr_agg_kernel(
    const int* __restrict__ row_ptr, const int* __restrict__ col,
    const float* __restrict__ hs, float* __restrict__ agg, int N){
  int node = (int)((blockIdx.x*256u + threadIdx.x) >> 5);
  int lane = threadIdx.x & 31;
  if (node >= N) return;
  int r0 = row_ptr[node];
  int r1 = row_ptr[node+1];
  float4 a0 = make_float4(0.f,0.f,0.f,0.f);
  float4 a1 = make_float4(0.f,0.f,0.f,0.f);
  float4 a2 = make_float4(0.f,0.f,0.f,0.f);
  float4 a3 = make_float4(0.f,0.f,0.f,0.f);
  int e = r0;
  for (; e + 3 < r1; e += 4){
    int s0 = col[e], s1 = col[e+1], s2 = col[e+2], s3 = col[e+3];
    float4 v0 = ((const float4*)(hs + (size_t)s0*128))[lane];
    float4 v1 = ((const float4*)(hs + (size_t)s1*128))[lane];
    float4 v2 = ((const float4*)(hs + (size_t)s2*128))[lane];
    float4 v3 = ((const float4*)(hs + (size_t)s3*128))[lane];
    a0.x += v0.x; a0.y += v0.y; a0.z += v0.z; a0.w += v0.w;
    a1.x += v1.x; a1.y += v1.y; a1.z += v1.z; a1.w += v1.w;
    a2.x += v2.x; a2.y += v2.y; a2.z += v2.z; a2.w += v2.w;
    a3.x += v3.x; a3.y += v3.y; a3.z += v3.z; a3.w += v3.w;
  }
  for (; e < r1; e++){
    int s0 = col[e];
    float4 v0 = ((const float4*)(hs + (size_t)s0*128))[lane];
    a0.x += v0.x; a0.y += v0.y; a0.z += v0.z; a0.w += v0.w;
  }
  float4 r;
  r.x = (a0.x + a1.x) + (a2.x + a3.x);
  r.y = (a0.y + a1.y) + (a2.y + a3.y);
  r.z = (a0.z + a1.z) + (a2.z + a3.z);
  r.w = (a0.w + a1.w) + (a2.w + a3.w);
  ((float4*)(agg + (size_t)node*128))[lane] = r;
}

// W prep: W[k][n] fp32 (128x128) -> Whi/Wlo bf16 stored transposed [n][k].
__global__ void wprep_kernel(const float* __restrict__ W,
                             __bf16* __restrict__ Whi, __bf16* __restrict__ Wlo){
  int idx = blockIdx.x*256 + threadIdx.x;   // 16384
  if (idx >= 128*128) return;
  int k = idx >> 7, n = idx & 127;
  float w = W[idx];
  __bf16 h = (__bf16)w;
  __bf16 l = (__bf16)(w - (float)h);
  Whi[n*128 + k] = h;
  Wlo[n*128 + k] = l;
}

// Split-bf16 MFMA GEMM: out[M x 128] = relu((A .* row_scale) @ W + bias) .* out_scale
// Fixed K=128, Ncols=128. Block = 256 thr = 4 waves; wave owns 32 rows x 128 cols
// as 2x8 tiles of 16x16, via mfma_f32_16x16x32_bf16. A fp32 split hi/lo on the
// fly; B from pre-split Whi/Wlo [n][k] (L1/L2-resident, no LDS).
// Layouts (m89/m120-verified): A/B frag: lane&15 = m/n, k = (lane>>4)*8+j;
// C/D: row = (lane>>4)*4+reg, col = lane&15.
__global__ __launch_bounds__(256) void mfma_gemm_kernel(
    const float* __restrict__ A,
    const __bf16* __restrict__ Whi, const __bf16* __restrict__ Wlo,
    const float* __restrict__ bias, const float* __restrict__ row_scale,
    const float* __restrict__ out_scale, float* __restrict__ out, int M){
  const int tid  = threadIdx.x;
  const int wv   = tid >> 6;
  const int lane = tid & 63;
  const int q    = lane >> 4;      // quad
  const int mn   = lane & 15;      // m (for A / D-col) or n (for B)
  const int row0 = blockIdx.x*128 + wv*32;

  f32x4 acc[2][8];
  #pragma unroll
  for (int mt = 0; mt < 2; mt++)
    #pragma unroll
    for (int nt = 0; nt < 8; nt++)
      acc[mt][nt] = (f32x4){0.f,0.f,0.f,0.f};

  float rs[2];
  #pragma unroll
  for (int mt = 0; mt < 2; mt++){
    int ridx = row0 + mt*16 + mn;
    if (ridx >= M) ridx = M - 1;
    rs[mt] = row_scale ? row_scale[ridx] : 1.f;
  }

  #pragma unroll
  for (int kc = 0; kc < 4; kc++){
    bf16x8 ah[2], al[2];
    #pragma unroll
    for (int mt = 0; mt < 2; mt++){
      const float* ap = A + (size_t)(row0 + mt*16 + mn)*128 + kc*32 + q*8;
      float4 x0 = *(const float4*)ap;
      float4 x1 = *(const float4*)(ap + 4);
      float v[8] = {x0.x, x0.y, x0.z, x0.w, x1.x, x1.y, x1.z, x1.w};
      #pragma unroll
      for (int j = 0; j < 8; j++){
        float s = v[j] * rs[mt];
        __bf16 h = (__bf16)s;
        ah[mt][j] = h;
        al[mt][j] = (__bf16)(s - (float)h);
      }
    }
    #pragma unroll
    for (int nt = 0; nt < 8; nt++){
      size_t boff = (size_t)(nt*16 + mn)*128 + kc*32 + q*8;
      bf16x8 bh = *(const bf16x8*)(Whi + boff);
      bf16x8 bl = *(const bf16x8*)(Wlo + boff);
      #pragma unroll
      for (int mt = 0; mt < 2; mt++){
        acc[mt][nt] = __builtin_amdgcn_mfma_f32_16x16x32_bf16(al[mt], bh, acc[mt][nt], 0, 0, 0);
        acc[mt][nt] = __builtin_amdgcn_mfma_f32_16x16x32_bf16(ah[mt], bl, acc[mt][nt], 0, 0, 0);
        acc[mt][nt] = __builtin_amdgcn_mfma_f32_16x16x32_bf16(ah[mt], bh, acc[mt][nt], 0, 0, 0);
      }
    }
  }

  #pragma unroll
  for (int mt = 0; mt < 2; mt++){
    #pragma unroll
    for (int r = 0; r < 4; r++){
      int gm = row0 + mt*16 + q*4 + r;
      if (gm < M){
        float osc = out_scale ? out_scale[gm] : 1.f;
        #pragma unroll
        for (int nt = 0; nt < 8; nt++){
          float v = acc[mt][nt][r] + bias[nt*16 + mn];
          v = fmaxf(v, 0.f) * osc;
          out[(size_t)gm*128 + nt*16 + mn] = v;
        }
      }
    }
  }
}

// Tiled fp32 SGEMM (MLP head only).
__global__ __launch_bounds__(256) void gemm_kernel(
    const float* __restrict__ A, const float* __restrict__ W,
    const float* __restrict__ bias, const float* __restrict__ row_scale,
    const float* __restrict__ out_scale, float* __restrict__ out,
    int M, int K, int Ncols, int do_relu){
  __shared__ float As[32][68];
  __shared__ float Bs[32][128];

  const int tid = threadIdx.x;
  const int tx = tid & 31;
  const int ty = tid >> 5;
  const int row0 = blockIdx.x * 64;
  const int col0 = blockIdx.y * 128;

  float acc[8][4];
  #pragma unroll
  for (int i = 0; i < 8; i++)
    #pragma unroll
    for (int j = 0; j < 4; j++) acc[i][j] = 0.f;

  for (int kb = 0; kb < K; kb += 32){
    #pragma unroll
    for (int i = 0; i < 2; i++){
      int flat = i*256 + tid;
      int m = flat >> 3, k4 = (flat & 7) << 2;
      int gm = row0 + m;
      float4 v = make_float4(0.f, 0.f, 0.f, 0.f);
      if (gm < M){
        v = *(const float4*)(A + (size_t)gm*K + kb + k4);
        if (row_scale){ float s = row_scale[gm]; v.x*=s; v.y*=s; v.z*=s; v.w*=s; }
      }
      As[k4+0][m] = v.x; As[k4+1][m] = v.y; As[k4+2][m] = v.z; As[k4+3][m] = v.w;
    }
    #pragma unroll
    for (int i = 0; i < 4; i++){
      int flat = i*256 + tid;
      int k = flat >> 5, j4 = (flat & 31) << 2;
      float4 v = *(const float4*)(W + (size_t)(kb + k)*Ncols + col0 + j4);
      *(float4*)&Bs[k][j4] = v;
    }
    __syncthreads();
    #pragma unroll
    for (int k = 0; k < 32; k++){
      float4 b = *(const float4*)&Bs[k][tx << 2];
      float a[8];
      #pragma unroll
      for (int i = 0; i < 8; i++) a[i] = As[k][ty*8 + i];
      #pragma unroll
      for (int i = 0; i < 8; i++){
        acc[i][0] = fmaf(a[i], b.x, acc[i][0]);
        acc[i][1] = fmaf(a[i], b.y, acc[i][1]);
        acc[i][2] = fmaf(a[i], b.z, acc[i][2]);
        acc[i][3] = fmaf(a[i], b.w, acc[i][3]);
      }
    }
    __syncthreads();
  }

  float4 bi = *(const float4*)(bias + col0 + (tx << 2));
  #pragma unroll
  for (int i = 0; i < 8; i++){
    int gm = row0 + ty*8 + i;
    if (gm < M){
      float4 v;
      v.x = acc[i][0] + bi.x; v.y = acc[i][1] + bi.y;
      v.z = acc[i][2] + bi.z; v.w = acc[i][3] + bi.w;
      if (do_relu){
        v.x = fmaxf(v.x, 0.f); v.y = fmaxf(v.y, 0.f);
        v.z = fmaxf(v.z, 0.f); v.w = fmaxf(v.w, 0.f);
      }
      if (out_scale){ float s = out_scale[gm]; v.x*=s; v.y*=s; v.z*=s; v.w*=s; }
      *(float4*)(out + (size_t)gm*Ncols + col0 + (tx << 2)) = v;
    }
  }
}

// Avg-pool per graph: graph_ids sorted -> binary search bounds, wave per graph.
__global__ void pool_kernel(const float* __restrict__ h, const int* __restrict__ gid,
                            float* __restrict__ emb, int N, int G){
  int g = blockIdx.x;
  int lane = threadIdx.x;   // 64 threads
  int lo = 0, hi = N;
  while (lo < hi){ int mid = (lo + hi) >> 1; if (gid[mid] < g) lo = mid + 1; else hi = mid; }
  int start = lo;
  hi = N;
  while (lo < hi){ int mid = (lo + hi) >> 1; if (gid[mid] <= g) lo = mid + 1; else hi = mid; }
  int end = lo;
  float ax = 0.f, ay = 0.f;
  for (int n = start; n < end; n++){
    float2 v = ((const float2*)(h + (size_t)n*128))[lane];
    ax += v.x; ay += v.y;
  }
  int c = end - start; if (c < 1) c = 1;
  float invc = 1.0f / (float)c;
  float2 r; r.x = ax * invc; r.y = ay * invc;
  ((float2*)(emb + (size_t)g*128))[lane] = r;
}

// Final 256->1: wave per graph, float4 per lane, shuffle reduce.
__global__ void final_dot_kernel(const float* __restrict__ x, const float* __restrict__ w,
                                 const float* __restrict__ b, float* __restrict__ out, int G){
  int idx = blockIdx.x*blockDim.x + threadIdx.x;
  int g = idx >> 6, lane = idx & 63;
  if (g >= G) return;
  float4 xv = ((const float4*)(x + (size_t)g*256))[lane];
  float4 wv = ((const float4*)w)[lane];
  float s = xv.x*wv.x + xv.y*wv.y + xv.z*wv.z + xv.w*wv.w;
  for (int off = 32; off > 0; off >>= 1) s += __shfl_down(s, off);
  if (lane == 0) out[g] = s + b[0];
}

extern "C" void kernel_launch(void* const* d_in, const int* in_sizes, int n_in,
                              void* d_out, int out_size, void* d_ws, size_t ws_size,
                              hipStream_t stream){
  const float* feats = (const float*)d_in[0];
  const int*   src   = (const int*)d_in[1];
  const int*   dst   = (const int*)d_in[2];
  const int*   gid   = (const int*)d_in[3];
  const float* W0 = (const float*)d_in[4];   const float* b0 = (const float*)d_in[5];
  const float* W1 = (const float*)d_in[6];   const float* b1 = (const float*)d_in[7];
  const float* W2 = (const float*)d_in[8];   const float* b2 = (const float*)d_in[9];
  const float* Wm0 = (const float*)d_in[10]; const float* bm0 = (const float*)d_in[11];
  const float* Wm1 = (const float*)d_in[12]; const float* bm1 = (const float*)d_in[13];
  const float* Wm2 = (const float*)d_in[14]; const float* bm2 = (const float*)d_in[15];
  float* out = (float*)d_out;

  const int E   = in_sizes[1];
  const int N   = in_sizes[3];
  const int G   = out_size;
  const int MH  = in_sizes[11];   // 512
  const int MH2 = in_sizes[13];   // 256
  const int NB  = ceil_div(N, 128);   // 782 for N=100000 (<= NBMAX)

  char* ws = (char*)d_ws;
  size_t off = 0;
  auto carve = [&](size_t bytes) -> char* {
    off = (off + 255) & ~(size_t)255;
    char* p = ws + off; off += bytes; return p;
  };
  float* inv_src = (float*)carve((size_t)N*4);
  float* inv_dst = (float*)carve((size_t)N*4);
  int* row_ptr = (int*)carve((size_t)(N+1)*4);
  int* col     = (int*)carve((size_t)E*4);
  __bf16* Wsp[6];
  for (int i = 0; i < 6; i++) Wsp[i] = (__bf16*)carve(128*128*2);
  float* hs  = (float*)carve((size_t)N*128*4);
  float* agg = (float*)carve((size_t)N*128*4);
  float* emb = (float*)carve((size_t)G*128*4);
  float* x1  = (float*)carve((size_t)G*MH*4);
  float* x2  = (float*)carve((size_t)G*MH2*4);

  // CSR-build temporaries alias agg (dead until first csr_agg writes it).
  unsigned* T = (unsigned*)agg;
  unsigned* cntA   = T;
  unsigned* cntB   = cntA + (size_t)B1*NB;
  unsigned* totals = cntB + (size_t)B1*NB;
  unsigned* baseA  = totals + 2*(size_t)NB;
  unsigned* baseB  = baseA + (NB+1);
  unsigned* bpack_d = baseB + (NB+1);
  unsigned char* bsrc_s = (unsigned char*)(bpack_d + E);

  bucket_count_kernel<<<B1, 256, 0, stream>>>(src, dst, cntA, cntB, E, NB);
  scan_cols_kernel<<<dim3(ceil_div(NB,256), 2), 256, 0, stream>>>(cntA, cntB, totals, NB);
  scan_base_kernel<<<1, NBMAX, 0, stream>>>(totals, baseA, baseB, NB, E);
  bucket_scatter_kernel<<<B1, 256, 0, stream>>>(src, dst, cntA, cntB, baseA, baseB,
                                                bpack_d, bsrc_s, E, NB);
  csr_finalize_kernel<<<NB, 256, 0, stream>>>(bpack_d, baseA, row_ptr, inv_dst, col, N, E, NB);
  degout_finalize_kernel<<<NB, 256, 0, stream>>>(bsrc_s, baseB, inv_src, N);
  wprep_kernel<<<64, 256, 0, stream>>>(W0, Wsp[0], Wsp[1]);
  wprep_kernel<<<64, 256, 0, stream>>>(W1, Wsp[2], Wsp[3]);
  wprep_kernel<<<64, 256, 0, stream>>>(W2, Wsp[4], Wsp[5]);
  scale_rows_kernel<<<ceil_div(N*32,256), 256, 0, stream>>>(feats, inv_src, hs, N*32);

  const int agg_blocks = ceil_div(N*32, 256);
  const int ggrid = ceil_div(N, 128);
  // layer 0: agg = CSR-sum(hs); hs = relu(agg*inv_dst @ W0 + b0) * inv_src
  csr_agg_kernel<<<agg_blocks, 256, 0, stream>>>(row_ptr, col, hs, agg, N);
  mfma_gemm_kernel<<<ggrid, 256, 0, stream>>>(agg, Wsp[0], Wsp[1], b0, inv_dst, inv_src, hs, N);
  // layer 1
  csr_agg_kernel<<<agg_blocks, 256, 0, stream>>>(row_ptr, col, hs, agg, N);
  mfma_gemm_kernel<<<ggrid, 256, 0, stream>>>(agg, Wsp[2], Wsp[3], b1, inv_dst, inv_src, hs, N);
  // layer 2 (no out_scale: plain h3 for pooling)
  csr_agg_kernel<<<agg_blocks, 256, 0, stream>>>(row_ptr, col, hs, agg, N);
  mfma_gemm_kernel<<<ggrid, 256, 0, stream>>>(agg, Wsp[4], Wsp[5], b2, inv_dst, nullptr, hs, N);
  // avg pooling
  pool_kernel<<<G, 64, 0, stream>>>(hs, gid, emb, N, G);
  // MLP head
  gemm_kernel<<<dim3(ceil_div(G,64), MH/128),  256, 0, stream>>>(emb, Wm0, bm0, nullptr, nullptr, x1, G, 128, MH, 1);
  gemm_kernel<<<dim3(ceil_div(G,64), MH2/128), 256, 0, stream>>>(x1, Wm1, bm1, nullptr, nullptr, x2, G, MH, MH2, 1);
  final_dot_kernel<<<ceil_div(G*64,256), 256, 0, stream>>>(x2, Wm2, bm2, out, G);
}

// Round 9
// 789.656 us; speedup vs baseline: 1.3884x; 1.0189x over previous
//
#include <hip/hip_runtime.h>

// ---------------------------------------------------------------------------
// GNN: 3x GraphConv (norm='both') + avg-pool + MLP(128->512->256->1), fp32.
// R9: tail consolidation on R8 (805us). csr_agg epilogue now applies inv_dst
// and writes agg as packed split-bf16 (hi<<16|lo, same 4B/elem) -> mfma_gemm
// just unpacks (no converts / row_scale in hot loop). Layer-0 gather scales
// by inv_src[src] inline (scale_rows kernel dropped). B1 256 (full-GPU
// count/scatter). degout merged into csr_finalize; one wprep launch.
// csr_agg pattern untouched: it is at its L2-duplication roofline
// (FETCH ~= 7x working set, ~3.75 TB/s fabric).
// ---------------------------------------------------------------------------

static inline int ceil_div(int a, int b){ return (a + b - 1) / b; }

#define B1 256          // pass-1 blocks
#define NBMAX 1024      // max buckets (N <= 131072; src ids fit in 17 bits)

typedef __bf16 bf16x8 __attribute__((ext_vector_type(8)));
typedef float  f32x4  __attribute__((ext_vector_type(4)));

static __device__ inline __bf16 bits_to_bf16(unsigned short u){
  union { unsigned short u; __bf16 b; } x; x.u = u; return x.b;
}
static __device__ inline unsigned short bf16_bits(__bf16 b){
  union { __bf16 b; unsigned short u; } x; x.b = b; return x.u;
}
static __device__ inline unsigned pack_split(float s){
  __bf16 h = (__bf16)s;
  __bf16 l = (__bf16)(s - (float)h);
  return ((unsigned)bf16_bits(h) << 16) | (unsigned)bf16_bits(l);
}

// Pass 1a: per-block bucket counts for dst (job A) and src (job B).
__global__ __launch_bounds__(256) void bucket_count_kernel(
    const int* __restrict__ src, const int* __restrict__ dst,
    unsigned* __restrict__ cntA, unsigned* __restrict__ cntB,
    int E, int NB){
  __shared__ unsigned la[NBMAX], lb[NBMAX];
  int t = threadIdx.x;
  for (int i = t; i < NB; i += 256){ la[i] = 0u; lb[i] = 0u; }
  __syncthreads();
  int chunk = (E + B1 - 1) / B1;
  int e0 = blockIdx.x * chunk, e1 = min(e0 + chunk, E);
  for (int e = e0 + t; e < e1; e += 256){
    atomicAdd(&la[dst[e] >> 7], 1u);
    atomicAdd(&lb[src[e] >> 7], 1u);
  }
  __syncthreads();
  for (int i = t; i < NB; i += 256){
    cntA[(size_t)blockIdx.x * NB + i] = la[i];
    cntB[(size_t)blockIdx.x * NB + i] = lb[i];
  }
}

// Column-wise exclusive scan over blocks for each bucket; emits totals.
__global__ void scan_cols_kernel(unsigned* __restrict__ cntA, unsigned* __restrict__ cntB,
                                 unsigned* __restrict__ totals, int NB){
  int b = blockIdx.x * 256 + threadIdx.x;
  if (b >= NB) return;
  unsigned* cnt = blockIdx.y ? cntB : cntA;
  unsigned run = 0;
  for (int blk = 0; blk < B1; blk++){
    unsigned v = cnt[(size_t)blk * NB + b];
    cnt[(size_t)blk * NB + b] = run;
    run += v;
  }
  totals[(size_t)blockIdx.y * NB + b] = run;
}

// Single-block exclusive scan of bucket totals -> baseA/baseB (each NB+1).
__global__ void scan_base_kernel(const unsigned* __restrict__ totals,
                                 unsigned* __restrict__ baseA, unsigned* __restrict__ baseB,
                                 int NB, int E){
  __shared__ unsigned s[NBMAX];
  int t = threadIdx.x;  // 1024 threads, NB <= 1024
  for (int job = 0; job < 2; job++){
    unsigned* base = job ? baseB : baseA;
    unsigned x = (t < NB) ? totals[(size_t)job * NB + t] : 0u;
    s[t] = x;
    __syncthreads();
    for (int off = 1; off < NBMAX; off <<= 1){
      unsigned v = (t >= off) ? s[t - off] : 0u;
      __syncthreads();
      s[t] += v;
      __syncthreads();
    }
    if (t < NB) base[t] = s[t] - x;
    if (t == 0) base[NB] = (unsigned)E;
    __syncthreads();
  }
}

// Pass 1b: scatter edges into bucketed arrays using per-block reserved offsets.
__global__ __launch_bounds__(256) void bucket_scatter_kernel(
    const int* __restrict__ src, const int* __restrict__ dst,
    const unsigned* __restrict__ cntA, const unsigned* __restrict__ cntB,
    const unsigned* __restrict__ baseA, const unsigned* __restrict__ baseB,
    unsigned* __restrict__ bpack_d, unsigned char* __restrict__ bsrc_s,
    int E, int NB){
  __shared__ unsigned curA[NBMAX], curB[NBMAX];
  int t = threadIdx.x;
  for (int i = t; i < NB; i += 256){
    curA[i] = baseA[i] + cntA[(size_t)blockIdx.x * NB + i];
    curB[i] = baseB[i] + cntB[(size_t)blockIdx.x * NB + i];
  }
  __syncthreads();
  int chunk = (E + B1 - 1) / B1;
  int e0 = blockIdx.x * chunk, e1 = min(e0 + chunk, E);
  for (int e = e0 + t; e < e1; e += 256){
    int s = src[e], d = dst[e];
    unsigned p = atomicAdd(&curA[d >> 7], 1u);
    bpack_d[p] = ((unsigned)(d & 127) << 17) | (unsigned)s;
    unsigned q = atomicAdd(&curB[s >> 7], 1u);
    bsrc_s[q] = (unsigned char)(s & 127);
  }
}

// Pass 2: per-bucket finalize. Job A: row_ptr, inv_dst, col scatter.
// Job B (merged degout): out-degree -> inv_src.
__global__ __launch_bounds__(256) void csr_finalize_kernel(
    const unsigned* __restrict__ bpack_d, const unsigned char* __restrict__ bsrc_s,
    const unsigned* __restrict__ baseA, const unsigned* __restrict__ baseB,
    int* __restrict__ row_ptr, float* __restrict__ inv_dst, float* __restrict__ inv_src,
    int* __restrict__ col, int N, int E, int NB){
  __shared__ unsigned cnt[128];
  __shared__ unsigned scn[128];
  int b = blockIdx.x, t = threadIdx.x;
  int node0 = b << 7;
  int nn = min(128, N - node0);
  int e0 = (int)baseA[b], e1 = (int)baseA[b + 1];
  if (t < 128) cnt[t] = 0u;
  __syncthreads();
  for (int e = e0 + t; e < e1; e += 256)
    atomicAdd(&cnt[(bpack_d[e] >> 17) & 127u], 1u);
  __syncthreads();
  unsigned mycnt = (t < 128) ? cnt[t] : 0u;
  if (t < 128) scn[t] = mycnt;
  __syncthreads();
  for (int off = 1; off < 128; off <<= 1){
    unsigned v = (t < 128 && t >= off) ? scn[t - off] : 0u;
    __syncthreads();
    if (t < 128) scn[t] += v;
    __syncthreads();
  }
  if (t < nn){
    unsigned excl = scn[t] - mycnt;
    row_ptr[node0 + t] = e0 + (int)excl;
    unsigned c = mycnt < 1u ? 1u : mycnt;
    inv_dst[node0 + t] = rsqrtf((float)c);
    cnt[t] = (unsigned)e0 + excl;   // reuse as cursor
  }
  if (b == NB - 1 && t == 0) row_ptr[N] = E;
  __syncthreads();
  for (int e = e0 + t; e < e1; e += 256){
    unsigned v = bpack_d[e];
    unsigned p = atomicAdd(&cnt[(v >> 17) & 127u], 1u);
    col[p] = (int)(v & 0x1FFFFu);
  }
  // ---- job B: out-degree ----
  __syncthreads();
  if (t < 128) cnt[t] = 0u;
  __syncthreads();
  int f0 = (int)baseB[b], f1 = (int)baseB[b + 1];
  for (int e = f0 + t; e < f1; e += 256)
    atomicAdd(&cnt[bsrc_s[e]], 1u);
  __syncthreads();
  if (t < nn){
    unsigned c = cnt[t] < 1u ? 1u : cnt[t];
    inv_src[node0 + t] = rsqrtf((float)c);
  }
}

// Half-wave (32 lanes) per node; lane owns a float4. Optional per-src scale
// (layer 0: feats * inv_src[src]). Epilogue: * inv_dst[node], packed split-bf16.
template<bool SC>
__global__ __launch_bounds__(256) void csr_agg_kernel(
    const int* __restrict__ row_ptr, const int* __restrict__ col,
    const float* __restrict__ hs, const float* __restrict__ scale,
    const float* __restrict__ inv_dst, unsigned* __restrict__ aggp, int N){
  int node = (int)((blockIdx.x*256u + threadIdx.x) >> 5);
  int lane = threadIdx.x & 31;
  if (node >= N) return;
  int r0 = row_ptr[node];
  int r1 = row_ptr[node+1];
  float4 a0 = make_float4(0.f,0.f,0.f,0.f);
  float4 a1 = make_float4(0.f,0.f,0.f,0.f);
  float4 a2 = make_float4(0.f,0.f,0.f,0.f);
  float4 a3 = make_float4(0.f,0.f,0.f,0.f);
  int e = r0;
  for (; e + 3 < r1; e += 4){
    int s0 = col[e], s1 = col[e+1], s2 = col[e+2], s3 = col[e+3];
    float4 v0 = ((const float4*)(hs + (size_t)s0*128))[lane];
    float4 v1 = ((const float4*)(hs + (size_t)s1*128))[lane];
    float4 v2 = ((const float4*)(hs + (size_t)s2*128))[lane];
    float4 v3 = ((const float4*)(hs + (size_t)s3*128))[lane];
    if (SC){
      float c0 = scale[s0], c1 = scale[s1], c2 = scale[s2], c3 = scale[s3];
      v0.x*=c0; v0.y*=c0; v0.z*=c0; v0.w*=c0;
      v1.x*=c1; v1.y*=c1; v1.z*=c1; v1.w*=c1;
      v2.x*=c2; v2.y*=c2; v2.z*=c2; v2.w*=c2;
      v3.x*=c3; v3.y*=c3; v3.z*=c3; v3.w*=c3;
    }
    a0.x += v0.x; a0.y += v0.y; a0.z += v0.z; a0.w += v0.w;
    a1.x += v1.x; a1.y += v1.y; a1.z += v1.z; a1.w += v1.w;
    a2.x += v2.x; a2.y += v2.y; a2.z += v2.z; a2.w += v2.w;
    a3.x += v3.x; a3.y += v3.y; a3.z += v3.z; a3.w += v3.w;
  }
  for (; e < r1; e++){
    int s0 = col[e];
    float4 v0 = ((const float4*)(hs + (size_t)s0*128))[lane];
    if (SC){ float c0 = scale[s0]; v0.x*=c0; v0.y*=c0; v0.z*=c0; v0.w*=c0; }
    a0.x += v0.x; a0.y += v0.y; a0.z += v0.z; a0.w += v0.w;
  }
  float idst = inv_dst[node];
  float rx = ((a0.x + a1.x) + (a2.x + a3.x)) * idst;
  float ry = ((a0.y + a1.y) + (a2.y + a3.y)) * idst;
  float rz = ((a0.z + a1.z) + (a2.z + a3.z)) * idst;
  float rw = ((a0.w + a1.w) + (a2.w + a3.w)) * idst;
  uint4 p;
  p.x = pack_split(rx); p.y = pack_split(ry);
  p.z = pack_split(rz); p.w = pack_split(rw);
  ((uint4*)(aggp + (size_t)node*128))[lane] = p;
}

// W prep (all 3 layers in one launch): W[k][n] fp32 -> Whi/Wlo bf16 [n][k].
__global__ void wprep_kernel(const float* __restrict__ W0, const float* __restrict__ W1,
                             const float* __restrict__ W2,
                             __bf16* __restrict__ Wsp){   // 6 x 128*128: hi0,lo0,hi1,lo1,hi2,lo2
  int gidx = blockIdx.x*256 + threadIdx.x;    // 3*16384
  if (gidx >= 3*128*128) return;
  int layer = gidx >> 14, idx = gidx & 16383;
  const float* W = layer == 0 ? W0 : (layer == 1 ? W1 : W2);
  int k = idx >> 7, n = idx & 127;
  float w = W[idx];
  __bf16 h = (__bf16)w;
  __bf16 l = (__bf16)(w - (float)h);
  Wsp[(size_t)layer*2*16384 + n*128 + k] = h;
  Wsp[(size_t)layer*2*16384 + 16384 + n*128 + k] = l;
}

// Split-bf16 MFMA GEMM on packed A: out = relu(A@W + bias) .* out_scale.
// A packed u32 (bf16hi<<16|bf16lo), already carries inv_dst. K=N=128.
__global__ __launch_bounds__(256) void mfma_gemm_kernel(
    const unsigned* __restrict__ A,
    const __bf16* __restrict__ Whi, const __bf16* __restrict__ Wlo,
    const float* __restrict__ bias, const float* __restrict__ out_scale,
    float* __restrict__ out, int M){
  const int tid  = threadIdx.x;
  const int wv   = tid >> 6;
  const int lane = tid & 63;
  const int q    = lane >> 4;      // quad
  const int mn   = lane & 15;      // m (for A / D-col) or n (for B)
  const int row0 = blockIdx.x*128 + wv*32;

  f32x4 acc[2][8];
  #pragma unroll
  for (int mt = 0; mt < 2; mt++)
    #pragma unroll
    for (int nt = 0; nt < 8; nt++)
      acc[mt][nt] = (f32x4){0.f,0.f,0.f,0.f};

  #pragma unroll
  for (int kc = 0; kc < 4; kc++){
    bf16x8 ah[2], al[2];
    #pragma unroll
    for (int mt = 0; mt < 2; mt++){
      const unsigned* ap = A + (size_t)(row0 + mt*16 + mn)*128 + kc*32 + q*8;
      uint4 x0 = *(const uint4*)ap;
      uint4 x1 = *(const uint4*)(ap + 4);
      unsigned v[8] = {x0.x, x0.y, x0.z, x0.w, x1.x, x1.y, x1.z, x1.w};
      #pragma unroll
      for (int j = 0; j < 8; j++){
        ah[mt][j] = bits_to_bf16((unsigned short)(v[j] >> 16));
        al[mt][j] = bits_to_bf16((unsigned short)(v[j] & 0xFFFFu));
      }
    }
    #pragma unroll
    for (int nt = 0; nt < 8; nt++){
      size_t boff = (size_t)(nt*16 + mn)*128 + kc*32 + q*8;
      bf16x8 bh = *(const bf16x8*)(Whi + boff);
      bf16x8 bl = *(const bf16x8*)(Wlo + boff);
      #pragma unroll
      for (int mt = 0; mt < 2; mt++){
        acc[mt][nt] = __builtin_amdgcn_mfma_f32_16x16x32_bf16(al[mt], bh, acc[mt][nt], 0, 0, 0);
        acc[mt][nt] = __builtin_amdgcn_mfma_f32_16x16x32_bf16(ah[mt], bl, acc[mt][nt], 0, 0, 0);
        acc[mt][nt] = __builtin_amdgcn_mfma_f32_16x16x32_bf16(ah[mt], bh, acc[mt][nt], 0, 0, 0);
      }
    }
  }

  #pragma unroll
  for (int mt = 0; mt < 2; mt++){
    #pragma unroll
    for (int r = 0; r < 4; r++){
      int gm = row0 + mt*16 + q*4 + r;
      if (gm < M){
        float osc = out_scale ? out_scale[gm] : 1.f;
        #pragma unroll
        for (int nt = 0; nt < 8; nt++){
          float v = acc[mt][nt][r] + bias[nt*16 + mn];
          v = fmaxf(v, 0.f) * osc;
          out[(size_t)gm*128 + nt*16 + mn] = v;
        }
      }
    }
  }
}

// Tiled fp32 SGEMM (MLP head only).
__global__ __launch_bounds__(256) void gemm_kernel(
    const float* __restrict__ A, const float* __restrict__ W,
    const float* __restrict__ bias, const float* __restrict__ row_scale,
    const float* __restrict__ out_scale, float* __restrict__ out,
    int M, int K, int Ncols, int do_relu){
  __shared__ float As[32][68];
  __shared__ float Bs[32][128];

  const int tid = threadIdx.x;
  const int tx = tid & 31;
  const int ty = tid >> 5;
  const int row0 = blockIdx.x * 64;
  const int col0 = blockIdx.y * 128;

  float acc[8][4];
  #pragma unroll
  for (int i = 0; i < 8; i++)
    #pragma unroll
    for (int j = 0; j < 4; j++) acc[i][j] = 0.f;

  for (int kb = 0; kb < K; kb += 32){
    #pragma unroll
    for (int i = 0; i < 2; i++){
      int flat = i*256 + tid;
      int m = flat >> 3, k4 = (flat & 7) << 2;
      int gm = row0 + m;
      float4 v = make_float4(0.f, 0.f, 0.f, 0.f);
      if (gm < M){
        v = *(const float4*)(A + (size_t)gm*K + kb + k4);
        if (row_scale){ float s = row_scale[gm]; v.x*=s; v.y*=s; v.z*=s; v.w*=s; }
      }
      As[k4+0][m] = v.x; As[k4+1][m] = v.y; As[k4+2][m] = v.z; As[k4+3][m] = v.w;
    }
    #pragma unroll
    for (int i = 0; i < 4; i++){
      int flat = i*256 + tid;
      int k = flat >> 5, j4 = (flat & 31) << 2;
      float4 v = *(const float4*)(W + (size_t)(kb + k)*Ncols + col0 + j4);
      *(float4*)&Bs[k][j4] = v;
    }
    __syncthreads();
    #pragma unroll
    for (int k = 0; k < 32; k++){
      float4 b = *(const float4*)&Bs[k][tx << 2];
      float a[8];
      #pragma unroll
      for (int i = 0; i < 8; i++) a[i] = As[k][ty*8 + i];
      #pragma unroll
      for (int i = 0; i < 8; i++){
        acc[i][0] = fmaf(a[i], b.x, acc[i][0]);
        acc[i][1] = fmaf(a[i], b.y, acc[i][1]);
        acc[i][2] = fmaf(a[i], b.z, acc[i][2]);
        acc[i][3] = fmaf(a[i], b.w, acc[i][3]);
      }
    }
    __syncthreads();
  }

  float4 bi = *(const float4*)(bias + col0 + (tx << 2));
  #pragma unroll
  for (int i = 0; i < 8; i++){
    int gm = row0 + ty*8 + i;
    if (gm < M){
      float4 v;
      v.x = acc[i][0] + bi.x; v.y = acc[i][1] + bi.y;
      v.z = acc[i][2] + bi.z; v.w = acc[i][3] + bi.w;
      if (do_relu){
        v.x = fmaxf(v.x, 0.f); v.y = fmaxf(v.y, 0.f);
        v.z = fmaxf(v.z, 0.f); v.w = fmaxf(v.w, 0.f);
      }
      if (out_scale){ float s = out_scale[gm]; v.x*=s; v.y*=s; v.z*=s; v.w*=s; }
      *(float4*)(out + (size_t)gm*Ncols + col0 + (tx << 2)) = v;
    }
  }
}

// Avg-pool per graph: graph_ids sorted -> binary search bounds, wave per graph.
__global__ void pool_kernel(const float* __restrict__ h, const int* __restrict__ gid,
                            float* __restrict__ emb, int N, int G){
  int g = blockIdx.x;
  int lane = threadIdx.x;   // 64 threads
  int lo = 0, hi = N;
  while (lo < hi){ int mid = (lo + hi) >> 1; if (gid[mid] < g) lo = mid + 1; else hi = mid; }
  int start = lo;
  hi = N;
  while (lo < hi){ int mid = (lo + hi) >> 1; if (gid[mid] <= g) lo = mid + 1; else hi = mid; }
  int end = lo;
  float ax = 0.f, ay = 0.f;
  for (int n = start; n < end; n++){
    float2 v = ((const float2*)(h + (size_t)n*128))[lane];
    ax += v.x; ay += v.y;
  }
  int c = end - start; if (c < 1) c = 1;
  float invc = 1.0f / (float)c;
  float2 r; r.x = ax * invc; r.y = ay * invc;
  ((float2*)(emb + (size_t)g*128))[lane] = r;
}

// Final 256->1: wave per graph, float4 per lane, shuffle reduce.
__global__ void final_dot_kernel(const float* __restrict__ x, const float* __restrict__ w,
                                 const float* __restrict__ b, float* __restrict__ out, int G){
  int idx = blockIdx.x*blockDim.x + threadIdx.x;
  int g = idx >> 6, lane = idx & 63;
  if (g >= G) return;
  float4 xv = ((const float4*)(x + (size_t)g*256))[lane];
  float4 wv = ((const float4*)w)[lane];
  float s = xv.x*wv.x + xv.y*wv.y + xv.z*wv.z + xv.w*wv.w;
  for (int off = 32; off > 0; off >>= 1) s += __shfl_down(s, off);
  if (lane == 0) out[g] = s + b[0];
}

extern "C" void kernel_launch(void* const* d_in, const int* in_sizes, int n_in,
                              void* d_out, int out_size, void* d_ws, size_t ws_size,
                              hipStream_t stream){
  const float* feats = (const float*)d_in[0];
  const int*   src   = (const int*)d_in[1];
  const int*   dst   = (const int*)d_in[2];
  const int*   gid   = (const int*)d_in[3];
  const float* W0 = (const float*)d_in[4];   const float* b0 = (const float*)d_in[5];
  const float* W1 = (const float*)d_in[6];   const float* b1 = (const float*)d_in[7];
  const float* W2 = (const float*)d_in[8];   const float* b2 = (const float*)d_in[9];
  const float* Wm0 = (const float*)d_in[10]; const float* bm0 = (const float*)d_in[11];
  const float* Wm1 = (const float*)d_in[12]; const float* bm1 = (const float*)d_in[13];
  const float* Wm2 = (const float*)d_in[14]; const float* bm2 = (const float*)d_in[15];
  float* out = (float*)d_out;

  const int E   = in_sizes[1];
  const int N   = in_sizes[3];
  const int G   = out_size;
  const int MH  = in_sizes[11];   // 512
  const int MH2 = in_sizes[13];   // 256
  const int NB  = ceil_div(N, 128);   // 782 for N=100000 (<= NBMAX)

  char* ws = (char*)d_ws;
  size_t off = 0;
  auto carve = [&](size_t bytes) -> char* {
    off = (off + 255) & ~(size_t)255;
    char* p = ws + off; off += bytes; return p;
  };
  float* inv_src = (float*)carve((size_t)N*4);
  float* inv_dst = (float*)carve((size_t)N*4);
  int* row_ptr = (int*)carve((size_t)(N+1)*4);
  int* col     = (int*)carve((size_t)E*4);
  __bf16* Wsp = (__bf16*)carve(6*128*128*2);   // hi0,lo0,hi1,lo1,hi2,lo2
  float* hs  = (float*)carve((size_t)N*128*4);
  unsigned* aggp = (unsigned*)carve((size_t)N*128*4);
  float* emb = (float*)carve((size_t)G*128*4);
  float* x1  = (float*)carve((size_t)G*MH*4);
  float* x2  = (float*)carve((size_t)G*MH2*4);

  // CSR-build temporaries alias aggp (dead until first csr_agg writes it).
  unsigned* T = (unsigned*)aggp;
  unsigned* cntA   = T;
  unsigned* cntB   = cntA + (size_t)B1*NB;
  unsigned* totals = cntB + (size_t)B1*NB;
  unsigned* baseA  = totals + 2*(size_t)NB;
  unsigned* baseB  = baseA + (NB+1);
  unsigned* bpack_d = baseB + (NB+1);
  unsigned char* bsrc_s = (unsigned char*)(bpack_d + E);

  bucket_count_kernel<<<B1, 256, 0, stream>>>(src, dst, cntA, cntB, E, NB);
  scan_cols_kernel<<<dim3(ceil_div(NB,256), 2), 256, 0, stream>>>(cntA, cntB, totals, NB);
  scan_base_kernel<<<1, NBMAX, 0, stream>>>(totals, baseA, baseB, NB, E);
  bucket_scatter_kernel<<<B1, 256, 0, stream>>>(src, dst, cntA, cntB, baseA, baseB,
                                                bpack_d, bsrc_s, E, NB);
  csr_finalize_kernel<<<NB, 256, 0, stream>>>(bpack_d, bsrc_s, baseA, baseB,
                                              row_ptr, inv_dst, inv_src, col, N, E, NB);
  wprep_kernel<<<192, 256, 0, stream>>>(W0, W1, W2, Wsp);

  const int agg_blocks = ceil_div(N*32, 256);
  const int ggrid = ceil_div(N, 128);
  __bf16 *Whi0 = Wsp,            *Wlo0 = Wsp + 16384;
  __bf16 *Whi1 = Wsp + 2*16384,  *Wlo1 = Wsp + 3*16384;
  __bf16 *Whi2 = Wsp + 4*16384,  *Wlo2 = Wsp + 5*16384;
  // layer 0: aggp = pack(inv_dst * sum(feats[s]*inv_src[s])); hs = relu(aggp@W0+b0)*inv_src
  csr_agg_kernel<true><<<agg_blocks, 256, 0, stream>>>(row_ptr, col, feats, inv_src, inv_dst, aggp, N);
  mfma_gemm_kernel<<<ggrid, 256, 0, stream>>>(aggp, Whi0, Wlo0, b0, inv_src, hs, N);
  // layer 1
  csr_agg_kernel<false><<<agg_blocks, 256, 0, stream>>>(row_ptr, col, hs, nullptr, inv_dst, aggp, N);
  mfma_gemm_kernel<<<ggrid, 256, 0, stream>>>(aggp, Whi1, Wlo1, b1, inv_src, hs, N);
  // layer 2 (no out_scale: plain h3 for pooling)
  csr_agg_kernel<false><<<agg_blocks, 256, 0, stream>>>(row_ptr, col, hs, nullptr, inv_dst, aggp, N);
  mfma_gemm_kernel<<<ggrid, 256, 0, stream>>>(aggp, Whi2, Wlo2, b2, nullptr, hs, N);
  // avg pooling
  pool_kernel<<<G, 64, 0, stream>>>(hs, gid, emb, N, G);
  // MLP head
  gemm_kernel<<<dim3(ceil_div(G,64), MH/128),  256, 0, stream>>>(emb, Wm0, bm0, nullptr, nullptr, x1, G, 128, MH, 1);
  gemm_kernel<<<dim3(ceil_div(G,64), MH2/128), 256, 0, stream>>>(x1, Wm1, bm1, nullptr, nullptr, x2, G, MH, MH2, 1);
  final_dot_kernel<<<ceil_div(G*64,256), 256, 0, stream>>>(x2, Wm2, bm2, out, G);
}

// Round 10
// 775.271 us; speedup vs baseline: 1.4141x; 1.0186x over previous
//
#include <hip/hip_runtime.h>

// ---------------------------------------------------------------------------
// GNN: 3x GraphConv (norm='both') + avg-pool + MLP(128->512->256->1), fp32.
// R10: eliminate ALL scattered global writes from the CSR build.
// scatter_count: one pass kernel = LDS hist -> LDS scan -> LDS staging ->
// coalesced block-major flush (+ per-(block,bucket) offsets to cntA/cntB).
// finalize: thread=block walks its segment (reads only; read sharing is
// cheap). Head: pool+MLP1+MLP2+dot fused into one kernel (LDS resident).
// csr_agg (structural roofline ~116us) and split-bf16 mfma_gemm unchanged.
// ---------------------------------------------------------------------------

static inline int ceil_div(int a, int b){ return (a + b - 1) / b; }

#define B1 256          // scatter blocks == blockDim of finalize (thread<->block)
#define NBMAX 1024      // max buckets (N <= 131072; src ids fit in 17 bits)
#define CHUNK_MAX 7168  // max edges per scatter block (E <= B1*CHUNK_MAX)
#define WPREP_BLOCKS 192

typedef __bf16 bf16x8 __attribute__((ext_vector_type(8)));
typedef float  f32x4  __attribute__((ext_vector_type(4)));

static __device__ inline __bf16 bits_to_bf16(unsigned short u){
  union { unsigned short u; __bf16 b; } x; x.u = u; return x.b;
}
static __device__ inline unsigned short bf16_bits(__bf16 b){
  union { __bf16 b; unsigned short u; } x; x.b = b; return x.u;
}
static __device__ inline unsigned pack_split(float s){
  __bf16 h = (__bf16)s;
  __bf16 l = (__bf16)(s - (float)h);
  return ((unsigned)bf16_bits(h) << 16) | (unsigned)bf16_bits(l);
}

// One-pass bucketed counting sort, block-local staging, coalesced flush.
// Also hosts wprep on blocks >= B1 (W fp32 -> split-bf16 [n][k]).
__global__ __launch_bounds__(256) void scatter_count_kernel(
    const int* __restrict__ src, const int* __restrict__ dst,
    unsigned* __restrict__ cntA, unsigned* __restrict__ cntB,
    unsigned* __restrict__ stagedA, unsigned char* __restrict__ stagedB,
    const float* __restrict__ W0, const float* __restrict__ W1,
    const float* __restrict__ W2, __bf16* __restrict__ Wsp,
    int E, int NB){
  if (blockIdx.x >= B1){
    int gidx = (blockIdx.x - B1)*256 + threadIdx.x;    // 3*16384
    if (gidx < 3*128*128){
      int layer = gidx >> 14, idx = gidx & 16383;
      const float* W = layer == 0 ? W0 : (layer == 1 ? W1 : W2);
      int k = idx >> 7, n = idx & 127;
      float w = W[idx];
      __bf16 h = (__bf16)w;
      __bf16 l = (__bf16)(w - (float)h);
      Wsp[(size_t)layer*2*16384 + n*128 + k] = h;
      Wsp[(size_t)layer*2*16384 + 16384 + n*128 + k] = l;
    }
    return;
  }

  __shared__ unsigned la[NBMAX], lb[NBMAX];
  __shared__ unsigned tsum[256];
  __shared__ unsigned stA[CHUNK_MAX];
  __shared__ unsigned char stB[CHUNK_MAX];

  const int t = threadIdx.x;
  const int blk = blockIdx.x;
  const int chunk = (E + B1 - 1) / B1;
  const int e0 = blk * chunk, e1 = min(e0 + chunk, E);
  const int len = e1 - e0;
  const int strideB = (chunk + 3) & ~3;

  #pragma unroll
  for (int i = t; i < NBMAX; i += 256){ la[i] = 0u; lb[i] = 0u; }
  __syncthreads();
  for (int e = e0 + t; e < e1; e += 256){
    atomicAdd(&la[dst[e] >> 7], 1u);
    atomicAdd(&lb[src[e] >> 7], 1u);
  }
  __syncthreads();

  // exclusive scan of la (job A), then lb (job B); offsets also to cntA/cntB.
  for (int job = 0; job < 2; job++){
    unsigned* lx = job ? lb : la;
    unsigned* cx = job ? cntB : cntA;
    int b4 = t*4;
    unsigned v0 = lx[b4], v1 = lx[b4+1], v2 = lx[b4+2], v3 = lx[b4+3];
    unsigned s = v0+v1+v2+v3;
    tsum[t] = s;
    __syncthreads();
    for (int off = 1; off < 256; off <<= 1){
      unsigned u = (t >= off) ? tsum[t-off] : 0u;
      __syncthreads();
      tsum[t] += u;
      __syncthreads();
    }
    unsigned run = tsum[t] - s;
    unsigned o0 = run, o1 = run+v0, o2 = run+v0+v1, o3 = run+v0+v1+v2;
    lx[b4] = o0; lx[b4+1] = o1; lx[b4+2] = o2; lx[b4+3] = o3;
    if (b4   < NB) cx[(size_t)blk*NB + b4  ] = o0;
    if (b4+1 < NB) cx[(size_t)blk*NB + b4+1] = o1;
    if (b4+2 < NB) cx[(size_t)blk*NB + b4+2] = o2;
    if (b4+3 < NB) cx[(size_t)blk*NB + b4+3] = o3;
    __syncthreads();
  }

  // placement into LDS staging (la/lb now cursors).
  for (int e = e0 + t; e < e1; e += 256){
    int s = src[e], d = dst[e];
    unsigned pA = atomicAdd(&la[d >> 7], 1u);
    stA[pA] = ((unsigned)(d & 127) << 17) | (unsigned)s;
    unsigned pB = atomicAdd(&lb[s >> 7], 1u);
    stB[pB] = (unsigned char)(s & 127);
  }
  __syncthreads();

  // coalesced flush
  for (int i = t; i < len; i += 256)
    stagedA[(size_t)blk*chunk + i] = stA[i];
  int w4 = (len + 3) >> 2;
  unsigned* gB = (unsigned*)(stagedB + (size_t)blk*strideB);
  for (int i = t; i < w4; i += 256)
    gB[i] = *(unsigned*)&stB[4*i];
}

// totals[job][b] = sum over blk of per-(blk,b) counts (diff of offsets).
__global__ void totals_kernel(const unsigned* __restrict__ cntA,
                              const unsigned* __restrict__ cntB,
                              unsigned* __restrict__ totals, int NB, int E){
  int b = blockIdx.x * 256 + threadIdx.x;
  if (b >= NB) return;
  const unsigned* cx = blockIdx.y ? cntB : cntA;
  const int chunk = (E + B1 - 1) / B1;
  unsigned run = 0;
  for (int blk = 0; blk < B1; blk++){
    int lenb = E - blk*chunk; if (lenb > chunk) lenb = chunk; if (lenb < 0) lenb = 0;
    unsigned cur = cx[(size_t)blk*NB + b];
    unsigned nxt = (b < NB-1) ? cx[(size_t)blk*NB + b + 1] : (unsigned)lenb;
    run += nxt - cur;
  }
  totals[(size_t)blockIdx.y*NB + b] = run;
}

// Single-block exclusive scan of bucket totals -> baseA/baseB (each NB+1).
__global__ void scan_base_kernel(const unsigned* __restrict__ totals,
                                 unsigned* __restrict__ baseA, unsigned* __restrict__ baseB,
                                 int NB, int E){
  __shared__ unsigned s[NBMAX];
  int t = threadIdx.x;  // 1024 threads, NB <= 1024
  for (int job = 0; job < 2; job++){
    unsigned* base = job ? baseB : baseA;
    unsigned x = (t < NB) ? totals[(size_t)job*NB + t] : 0u;
    s[t] = x;
    __syncthreads();
    for (int off = 1; off < NBMAX; off <<= 1){
      unsigned v = (t >= off) ? s[t - off] : 0u;
      __syncthreads();
      s[t] += v;
      __syncthreads();
    }
    if (t < NB) base[t] = s[t] - x;
    if (t == 0) base[NB] = (unsigned)E;
    __syncthreads();
  }
}

// Per-bucket finalize: thread t walks scatter-block t's segment for this bucket.
// Job A: row_ptr, inv_dst, col. Job B: inv_src.
__global__ __launch_bounds__(256) void csr_finalize_kernel(
    const unsigned* __restrict__ stagedA, const unsigned char* __restrict__ stagedB,
    const unsigned* __restrict__ cntA, const unsigned* __restrict__ cntB,
    const unsigned* __restrict__ baseA,
    int* __restrict__ row_ptr, float* __restrict__ inv_dst, float* __restrict__ inv_src,
    int* __restrict__ col, int N, int E, int NB){
  __shared__ unsigned cnt[128];
  __shared__ unsigned scn[128];
  const int b = blockIdx.x, t = threadIdx.x;   // t <-> scatter block (B1==256)
  const int node0 = b << 7;
  const int nn = min(128, N - node0);
  const int chunk = (E + B1 - 1) / B1;
  const int strideB = (chunk + 3) & ~3;
  int lenb = E - t*chunk; if (lenb > chunk) lenb = chunk; if (lenb < 0) lenb = 0;

  const unsigned a0 = cntA[(size_t)t*NB + b];
  const unsigned a1 = (b < NB-1) ? cntA[(size_t)t*NB + b + 1] : (unsigned)lenb;
  const unsigned* segA = stagedA + (size_t)t*chunk;

  if (t < 128) cnt[t] = 0u;
  __syncthreads();
  for (unsigned i = a0; i < a1; i++)
    atomicAdd(&cnt[(segA[i] >> 17) & 127u], 1u);
  __syncthreads();
  unsigned mycnt = (t < 128) ? cnt[t] : 0u;
  if (t < 128) scn[t] = mycnt;
  __syncthreads();
  for (int off = 1; off < 128; off <<= 1){
    unsigned v = (t < 128 && t >= off) ? scn[t - off] : 0u;
    __syncthreads();
    if (t < 128) scn[t] += v;
    __syncthreads();
  }
  int e0 = (int)baseA[b];
  if (t < nn){
    unsigned excl = scn[t] - mycnt;
    row_ptr[node0 + t] = e0 + (int)excl;
    unsigned c = mycnt < 1u ? 1u : mycnt;
    inv_dst[node0 + t] = rsqrtf((float)c);
    cnt[t] = (unsigned)e0 + excl;   // reuse as cursor
  }
  if (b == NB - 1 && t == 0) row_ptr[N] = E;
  __syncthreads();
  for (unsigned i = a0; i < a1; i++){
    unsigned v = segA[i];
    unsigned p = atomicAdd(&cnt[(v >> 17) & 127u], 1u);
    col[p] = (int)(v & 0x1FFFFu);
  }
  // ---- job B: out-degree -> inv_src ----
  __syncthreads();
  if (t < 128) cnt[t] = 0u;
  __syncthreads();
  const unsigned b0o = cntB[(size_t)t*NB + b];
  const unsigned b1o = (b < NB-1) ? cntB[(size_t)t*NB + b + 1] : (unsigned)lenb;
  const unsigned char* segB = stagedB + (size_t)t*strideB;
  for (unsigned i = b0o; i < b1o; i++)
    atomicAdd(&cnt[segB[i]], 1u);
  __syncthreads();
  if (t < nn){
    unsigned c = cnt[t] < 1u ? 1u : cnt[t];
    inv_src[node0 + t] = rsqrtf((float)c);
  }
}

// Half-wave (32 lanes) per node; lane owns a float4. Optional per-src scale
// (layer 0: feats * inv_src[src]). Epilogue: * inv_dst[node], packed split-bf16.
template<bool SC>
__global__ __launch_bounds__(256) void csr_agg_kernel(
    const int* __restrict__ row_ptr, const int* __restrict__ col,
    const float* __restrict__ hs, const float* __restrict__ scale,
    const float* __restrict__ inv_dst, unsigned* __restrict__ aggp, int N){
  int node = (int)((blockIdx.x*256u + threadIdx.x) >> 5);
  int lane = threadIdx.x & 31;
  if (node >= N) return;
  int r0 = row_ptr[node];
  int r1 = row_ptr[node+1];
  float4 a0 = make_float4(0.f,0.f,0.f,0.f);
  float4 a1 = make_float4(0.f,0.f,0.f,0.f);
  float4 a2 = make_float4(0.f,0.f,0.f,0.f);
  float4 a3 = make_float4(0.f,0.f,0.f,0.f);
  int e = r0;
  for (; e + 3 < r1; e += 4){
    int s0 = col[e], s1 = col[e+1], s2 = col[e+2], s3 = col[e+3];
    float4 v0 = ((const float4*)(hs + (size_t)s0*128))[lane];
    float4 v1 = ((const float4*)(hs + (size_t)s1*128))[lane];
    float4 v2 = ((const float4*)(hs + (size_t)s2*128))[lane];
    float4 v3 = ((const float4*)(hs + (size_t)s3*128))[lane];
    if (SC){
      float c0 = scale[s0], c1 = scale[s1], c2 = scale[s2], c3 = scale[s3];
      v0.x*=c0; v0.y*=c0; v0.z*=c0; v0.w*=c0;
      v1.x*=c1; v1.y*=c1; v1.z*=c1; v1.w*=c1;
      v2.x*=c2; v2.y*=c2; v2.z*=c2; v2.w*=c2;
      v3.x*=c3; v3.y*=c3; v3.z*=c3; v3.w*=c3;
    }
    a0.x += v0.x; a0.y += v0.y; a0.z += v0.z; a0.w += v0.w;
    a1.x += v1.x; a1.y += v1.y; a1.z += v1.z; a1.w += v1.w;
    a2.x += v2.x; a2.y += v2.y; a2.z += v2.z; a2.w += v2.w;
    a3.x += v3.x; a3.y += v3.y; a3.z += v3.z; a3.w += v3.w;
  }
  for (; e < r1; e++){
    int s0 = col[e];
    float4 v0 = ((const float4*)(hs + (size_t)s0*128))[lane];
    if (SC){ float c0 = scale[s0]; v0.x*=c0; v0.y*=c0; v0.z*=c0; v0.w*=c0; }
    a0.x += v0.x; a0.y += v0.y; a0.z += v0.z; a0.w += v0.w;
  }
  float idst = inv_dst[node];
  float rx = ((a0.x + a1.x) + (a2.x + a3.x)) * idst;
  float ry = ((a0.y + a1.y) + (a2.y + a3.y)) * idst;
  float rz = ((a0.z + a1.z) + (a2.z + a3.z)) * idst;
  float rw = ((a0.w + a1.w) + (a2.w + a3.w)) * idst;
  uint4 p;
  p.x = pack_split(rx); p.y = pack_split(ry);
  p.z = pack_split(rz); p.w = pack_split(rw);
  ((uint4*)(aggp + (size_t)node*128))[lane] = p;
}

// Split-bf16 MFMA GEMM on packed A: out = relu(A@W + bias) .* out_scale.
__global__ __launch_bounds__(256) void mfma_gemm_kernel(
    const unsigned* __restrict__ A,
    const __bf16* __restrict__ Whi, const __bf16* __restrict__ Wlo,
    const float* __restrict__ bias, const float* __restrict__ out_scale,
    float* __restrict__ out, int M){
  const int tid  = threadIdx.x;
  const int wv   = tid >> 6;
  const int lane = tid & 63;
  const int q    = lane >> 4;
  const int mn   = lane & 15;
  const int row0 = blockIdx.x*128 + wv*32;

  f32x4 acc[2][8];
  #pragma unroll
  for (int mt = 0; mt < 2; mt++)
    #pragma unroll
    for (int nt = 0; nt < 8; nt++)
      acc[mt][nt] = (f32x4){0.f,0.f,0.f,0.f};

  #pragma unroll
  for (int kc = 0; kc < 4; kc++){
    bf16x8 ah[2], al[2];
    #pragma unroll
    for (int mt = 0; mt < 2; mt++){
      const unsigned* ap = A + (size_t)(row0 + mt*16 + mn)*128 + kc*32 + q*8;
      uint4 x0 = *(const uint4*)ap;
      uint4 x1 = *(const uint4*)(ap + 4);
      unsigned v[8] = {x0.x, x0.y, x0.z, x0.w, x1.x, x1.y, x1.z, x1.w};
      #pragma unroll
      for (int j = 0; j < 8; j++){
        ah[mt][j] = bits_to_bf16((unsigned short)(v[j] >> 16));
        al[mt][j] = bits_to_bf16((unsigned short)(v[j] & 0xFFFFu));
      }
    }
    #pragma unroll
    for (int nt = 0; nt < 8; nt++){
      size_t boff = (size_t)(nt*16 + mn)*128 + kc*32 + q*8;
      bf16x8 bh = *(const bf16x8*)(Whi + boff);
      bf16x8 bl = *(const bf16x8*)(Wlo + boff);
      #pragma unroll
      for (int mt = 0; mt < 2; mt++){
        acc[mt][nt] = __builtin_amdgcn_mfma_f32_16x16x32_bf16(al[mt], bh, acc[mt][nt], 0, 0, 0);
        acc[mt][nt] = __builtin_amdgcn_mfma_f32_16x16x32_bf16(ah[mt], bl, acc[mt][nt], 0, 0, 0);
        acc[mt][nt] = __builtin_amdgcn_mfma_f32_16x16x32_bf16(ah[mt], bh, acc[mt][nt], 0, 0, 0);
      }
    }
  }

  #pragma unroll
  for (int mt = 0; mt < 2; mt++){
    #pragma unroll
    for (int r = 0; r < 4; r++){
      int gm = row0 + mt*16 + q*4 + r;
      if (gm < M){
        float osc = out_scale ? out_scale[gm] : 1.f;
        #pragma unroll
        for (int nt = 0; nt < 8; nt++){
          float v = acc[mt][nt][r] + bias[nt*16 + mn];
          v = fmaxf(v, 0.f) * osc;
          out[(size_t)gm*128 + nt*16 + mn] = v;
        }
      }
    }
  }
}

// Fused head: avg-pool (8 graphs/block) + MLP 128->512->256->1, all in LDS.
__global__ __launch_bounds__(256) void head_kernel(
    const float* __restrict__ h, const int* __restrict__ gid,
    const float* __restrict__ Wm0, const float* __restrict__ bm0,
    const float* __restrict__ Wm1, const float* __restrict__ bm1,
    const float* __restrict__ Wm2, const float* __restrict__ bm2,
    float* __restrict__ out, int N, int G){
  __shared__ float embL[8][128];
  __shared__ float x1L[8][512];
  __shared__ float x2L[8][256];

  const int t = threadIdx.x;
  const int wave = t >> 6, lane = t & 63;
  const int g0 = blockIdx.x * 8;

  // pool: wave w handles graphs 2w, 2w+1
  for (int gg = 0; gg < 2; gg++){
    int gl = wave*2 + gg;
    int g = g0 + gl;
    float ax = 0.f, ay = 0.f;
    int start = 0, end = 0;
    if (g < G){
      int lo = 0, hi = N;
      while (lo < hi){ int mid = (lo + hi) >> 1; if (gid[mid] < g) lo = mid + 1; else hi = mid; }
      start = lo;
      hi = N;
      while (lo < hi){ int mid = (lo + hi) >> 1; if (gid[mid] <= g) lo = mid + 1; else hi = mid; }
      end = lo;
      for (int n = start; n < end; n++){
        float2 v = ((const float2*)(h + (size_t)n*128))[lane];
        ax += v.x; ay += v.y;
      }
    }
    int c = end - start; if (c < 1) c = 1;
    float invc = 1.0f / (float)c;
    embL[gl][2*lane]   = ax * invc;
    embL[gl][2*lane+1] = ay * invc;
  }
  __syncthreads();

  // MLP1: x1 = relu(emb @ Wm0 + bm0); thread t owns cols j0=t, j1=t+256
  {
    float acc[8][2];
    #pragma unroll
    for (int g = 0; g < 8; g++){ acc[g][0] = 0.f; acc[g][1] = 0.f; }
    for (int k = 0; k < 128; k++){
      float w0 = Wm0[(size_t)k*512 + t];
      float w1 = Wm0[(size_t)k*512 + t + 256];
      #pragma unroll
      for (int g = 0; g < 8; g++){
        float e = embL[g][k];
        acc[g][0] = fmaf(e, w0, acc[g][0]);
        acc[g][1] = fmaf(e, w1, acc[g][1]);
      }
    }
    float b0v = bm0[t], b1v = bm0[t + 256];
    #pragma unroll
    for (int g = 0; g < 8; g++){
      x1L[g][t]       = fmaxf(acc[g][0] + b0v, 0.f);
      x1L[g][t + 256] = fmaxf(acc[g][1] + b1v, 0.f);
    }
  }
  __syncthreads();

  // MLP2: x2 = relu(x1 @ Wm1 + bm1); thread t owns col j=t
  {
    float acc[8];
    #pragma unroll
    for (int g = 0; g < 8; g++) acc[g] = 0.f;
    for (int k = 0; k < 512; k++){
      float w = Wm1[(size_t)k*256 + t];
      #pragma unroll
      for (int g = 0; g < 8; g++)
        acc[g] = fmaf(x1L[g][k], w, acc[g]);
    }
    float bv = bm1[t];
    #pragma unroll
    for (int g = 0; g < 8; g++)
      x2L[g][t] = fmaxf(acc[g] + bv, 0.f);
  }
  __syncthreads();

  // final dot: 32 threads per graph, shfl-reduce width 32
  {
    int g = t >> 5;          // 0..7
    int c = t & 31;
    float s = 0.f;
    for (int i = c; i < 256; i += 32)
      s = fmaf(x2L[g][i], Wm2[i], s);
    for (int off = 16; off > 0; off >>= 1) s += __shfl_down(s, off, 32);
    if (c == 0 && (g0 + g) < G) out[g0 + g] = s + bm2[0];
  }
}

extern "C" void kernel_launch(void* const* d_in, const int* in_sizes, int n_in,
                              void* d_out, int out_size, void* d_ws, size_t ws_size,
                              hipStream_t stream){
  const float* feats = (const float*)d_in[0];
  const int*   src   = (const int*)d_in[1];
  const int*   dst   = (const int*)d_in[2];
  const int*   gid   = (const int*)d_in[3];
  const float* W0 = (const float*)d_in[4];   const float* b0 = (const float*)d_in[5];
  const float* W1 = (const float*)d_in[6];   const float* b1 = (const float*)d_in[7];
  const float* W2 = (const float*)d_in[8];   const float* b2 = (const float*)d_in[9];
  const float* Wm0 = (const float*)d_in[10]; const float* bm0 = (const float*)d_in[11];
  const float* Wm1 = (const float*)d_in[12]; const float* bm1 = (const float*)d_in[13];
  const float* Wm2 = (const float*)d_in[14]; const float* bm2 = (const float*)d_in[15];
  float* out = (float*)d_out;

  const int E   = in_sizes[1];
  const int N   = in_sizes[3];
  const int G   = out_size;
  const int NB  = ceil_div(N, 128);
  const int chunk = ceil_div(E, B1);
  const int strideB = (chunk + 3) & ~3;

  char* ws = (char*)d_ws;
  size_t off = 0;
  auto carve = [&](size_t bytes) -> char* {
    off = (off + 255) & ~(size_t)255;
    char* p = ws + off; off += bytes; return p;
  };
  float* inv_src = (float*)carve((size_t)N*4);
  float* inv_dst = (float*)carve((size_t)N*4);
  int* row_ptr = (int*)carve((size_t)(N+1)*4);
  int* col     = (int*)carve((size_t)E*4);
  __bf16* Wsp = (__bf16*)carve(6*128*128*2);   // hi0,lo0,hi1,lo1,hi2,lo2
  float* hs  = (float*)carve((size_t)N*128*4);
  unsigned* aggp = (unsigned*)carve((size_t)N*128*4);

  // CSR-build temporaries alias aggp (dead until first csr_agg writes it).
  unsigned* T = (unsigned*)aggp;
  unsigned* cntA   = T;
  unsigned* cntB   = cntA + (size_t)B1*NB;
  unsigned* totals = cntB + (size_t)B1*NB;
  unsigned* baseA  = totals + 2*(size_t)NB;
  unsigned* baseB  = baseA + (NB+1);
  unsigned* stagedA = baseB + (NB+1);
  unsigned char* stagedB = (unsigned char*)(stagedA + (size_t)B1*chunk);

  scatter_count_kernel<<<B1 + WPREP_BLOCKS, 256, 0, stream>>>(
      src, dst, cntA, cntB, stagedA, stagedB, W0, W1, W2, Wsp, E, NB);
  totals_kernel<<<dim3(ceil_div(NB,256), 2), 256, 0, stream>>>(cntA, cntB, totals, NB, E);
  scan_base_kernel<<<1, NBMAX, 0, stream>>>(totals, baseA, baseB, NB, E);
  csr_finalize_kernel<<<NB, 256, 0, stream>>>(stagedA, stagedB, cntA, cntB, baseA,
                                              row_ptr, inv_dst, inv_src, col, N, E, NB);

  const int agg_blocks = ceil_div(N*32, 256);
  const int ggrid = ceil_div(N, 128);
  __bf16 *Whi0 = Wsp,            *Wlo0 = Wsp + 16384;
  __bf16 *Whi1 = Wsp + 2*16384,  *Wlo1 = Wsp + 3*16384;
  __bf16 *Whi2 = Wsp + 4*16384,  *Wlo2 = Wsp + 5*16384;
  // layer 0
  csr_agg_kernel<true><<<agg_blocks, 256, 0, stream>>>(row_ptr, col, feats, inv_src, inv_dst, aggp, N);
  mfma_gemm_kernel<<<ggrid, 256, 0, stream>>>(aggp, Whi0, Wlo0, b0, inv_src, hs, N);
  // layer 1
  csr_agg_kernel<false><<<agg_blocks, 256, 0, stream>>>(row_ptr, col, hs, nullptr, inv_dst, aggp, N);
  mfma_gemm_kernel<<<ggrid, 256, 0, stream>>>(aggp, Whi1, Wlo1, b1, inv_src, hs, N);
  // layer 2 (no out_scale)
  csr_agg_kernel<false><<<agg_blocks, 256, 0, stream>>>(row_ptr, col, hs, nullptr, inv_dst, aggp, N);
  mfma_gemm_kernel<<<ggrid, 256, 0, stream>>>(aggp, Whi2, Wlo2, b2, nullptr, hs, N);
  // fused pool + MLP head
  head_kernel<<<ceil_div(G,8), 256, 0, stream>>>(hs, gid, Wm0, bm0, Wm1, bm1, Wm2, bm2, out, N, G);
}

// Round 11
// 721.457 us; speedup vs baseline: 1.5196x; 1.0746x over previous
//
#include <hip/hip_runtime.h>

// ---------------------------------------------------------------------------
// GNN: 3x GraphConv (norm='both') + avg-pool + MLP(128->512->256->1), fp32.
// R11: mfma_gemm stages Whi/Wlo into LDS (padded stride 136 bf16 ->
// conflict-free ds_read_b128) instead of per-lane scattered 16B global
// fragment loads (the inferred ~60-110us latency-bound hidden cost).
// Everything else identical to R10 (775us): counting-sort CSR build with
// LDS staging, roofline csr_agg (~116us x3), fused head.
// ---------------------------------------------------------------------------

static inline int ceil_div(int a, int b){ return (a + b - 1) / b; }

#define B1 256          // scatter blocks == blockDim of finalize (thread<->block)
#define NBMAX 1024      // max buckets (N <= 131072; src ids fit in 17 bits)
#define CHUNK_MAX 7168  // max edges per scatter block (E <= B1*CHUNK_MAX)
#define WPREP_BLOCKS 192

typedef __bf16 bf16x8 __attribute__((ext_vector_type(8)));
typedef float  f32x4  __attribute__((ext_vector_type(4)));

static __device__ inline __bf16 bits_to_bf16(unsigned short u){
  union { unsigned short u; __bf16 b; } x; x.u = u; return x.b;
}
static __device__ inline unsigned short bf16_bits(__bf16 b){
  union { __bf16 b; unsigned short u; } x; x.b = b; return x.u;
}
static __device__ inline unsigned pack_split(float s){
  __bf16 h = (__bf16)s;
  __bf16 l = (__bf16)(s - (float)h);
  return ((unsigned)bf16_bits(h) << 16) | (unsigned)bf16_bits(l);
}

// One-pass bucketed counting sort, block-local staging, coalesced flush.
// Also hosts wprep on blocks >= B1 (W fp32 -> split-bf16 [n][k]).
__global__ __launch_bounds__(256) void scatter_count_kernel(
    const int* __restrict__ src, const int* __restrict__ dst,
    unsigned* __restrict__ cntA, unsigned* __restrict__ cntB,
    unsigned* __restrict__ stagedA, unsigned char* __restrict__ stagedB,
    const float* __restrict__ W0, const float* __restrict__ W1,
    const float* __restrict__ W2, __bf16* __restrict__ Wsp,
    int E, int NB){
  if (blockIdx.x >= B1){
    int gidx = (blockIdx.x - B1)*256 + threadIdx.x;    // 3*16384
    if (gidx < 3*128*128){
      int layer = gidx >> 14, idx = gidx & 16383;
      const float* W = layer == 0 ? W0 : (layer == 1 ? W1 : W2);
      int k = idx >> 7, n = idx & 127;
      float w = W[idx];
      __bf16 h = (__bf16)w;
      __bf16 l = (__bf16)(w - (float)h);
      Wsp[(size_t)layer*2*16384 + n*128 + k] = h;
      Wsp[(size_t)layer*2*16384 + 16384 + n*128 + k] = l;
    }
    return;
  }

  __shared__ unsigned la[NBMAX], lb[NBMAX];
  __shared__ unsigned tsum[256];
  __shared__ unsigned stA[CHUNK_MAX];
  __shared__ unsigned char stB[CHUNK_MAX];

  const int t = threadIdx.x;
  const int blk = blockIdx.x;
  const int chunk = (E + B1 - 1) / B1;
  const int e0 = blk * chunk, e1 = min(e0 + chunk, E);
  const int len = e1 - e0;
  const int strideB = (chunk + 3) & ~3;

  #pragma unroll
  for (int i = t; i < NBMAX; i += 256){ la[i] = 0u; lb[i] = 0u; }
  __syncthreads();
  for (int e = e0 + t; e < e1; e += 256){
    atomicAdd(&la[dst[e] >> 7], 1u);
    atomicAdd(&lb[src[e] >> 7], 1u);
  }
  __syncthreads();

  // exclusive scan of la (job A), then lb (job B); offsets also to cntA/cntB.
  for (int job = 0; job < 2; job++){
    unsigned* lx = job ? lb : la;
    unsigned* cx = job ? cntB : cntA;
    int b4 = t*4;
    unsigned v0 = lx[b4], v1 = lx[b4+1], v2 = lx[b4+2], v3 = lx[b4+3];
    unsigned s = v0+v1+v2+v3;
    tsum[t] = s;
    __syncthreads();
    for (int off = 1; off < 256; off <<= 1){
      unsigned u = (t >= off) ? tsum[t-off] : 0u;
      __syncthreads();
      tsum[t] += u;
      __syncthreads();
    }
    unsigned run = tsum[t] - s;
    unsigned o0 = run, o1 = run+v0, o2 = run+v0+v1, o3 = run+v0+v1+v2;
    lx[b4] = o0; lx[b4+1] = o1; lx[b4+2] = o2; lx[b4+3] = o3;
    if (b4   < NB) cx[(size_t)blk*NB + b4  ] = o0;
    if (b4+1 < NB) cx[(size_t)blk*NB + b4+1] = o1;
    if (b4+2 < NB) cx[(size_t)blk*NB + b4+2] = o2;
    if (b4+3 < NB) cx[(size_t)blk*NB + b4+3] = o3;
    __syncthreads();
  }

  // placement into LDS staging (la/lb now cursors).
  for (int e = e0 + t; e < e1; e += 256){
    int s = src[e], d = dst[e];
    unsigned pA = atomicAdd(&la[d >> 7], 1u);
    stA[pA] = ((unsigned)(d & 127) << 17) | (unsigned)s;
    unsigned pB = atomicAdd(&lb[s >> 7], 1u);
    stB[pB] = (unsigned char)(s & 127);
  }
  __syncthreads();

  // coalesced flush
  for (int i = t; i < len; i += 256)
    stagedA[(size_t)blk*chunk + i] = stA[i];
  int w4 = (len + 3) >> 2;
  unsigned* gB = (unsigned*)(stagedB + (size_t)blk*strideB);
  for (int i = t; i < w4; i += 256)
    gB[i] = *(unsigned*)&stB[4*i];
}

// totals[job][b] = sum over blk of per-(blk,b) counts (diff of offsets).
__global__ void totals_kernel(const unsigned* __restrict__ cntA,
                              const unsigned* __restrict__ cntB,
                              unsigned* __restrict__ totals, int NB, int E){
  int b = blockIdx.x * 256 + threadIdx.x;
  if (b >= NB) return;
  const unsigned* cx = blockIdx.y ? cntB : cntA;
  const int chunk = (E + B1 - 1) / B1;
  unsigned run = 0;
  for (int blk = 0; blk < B1; blk++){
    int lenb = E - blk*chunk; if (lenb > chunk) lenb = chunk; if (lenb < 0) lenb = 0;
    unsigned cur = cx[(size_t)blk*NB + b];
    unsigned nxt = (b < NB-1) ? cx[(size_t)blk*NB + b + 1] : (unsigned)lenb;
    run += nxt - cur;
  }
  totals[(size_t)blockIdx.y*NB + b] = run;
}

// Single-block exclusive scan of bucket totals -> baseA/baseB (each NB+1).
__global__ void scan_base_kernel(const unsigned* __restrict__ totals,
                                 unsigned* __restrict__ baseA, unsigned* __restrict__ baseB,
                                 int NB, int E){
  __shared__ unsigned s[NBMAX];
  int t = threadIdx.x;  // 1024 threads, NB <= 1024
  for (int job = 0; job < 2; job++){
    unsigned* base = job ? baseB : baseA;
    unsigned x = (t < NB) ? totals[(size_t)job*NB + t] : 0u;
    s[t] = x;
    __syncthreads();
    for (int off = 1; off < NBMAX; off <<= 1){
      unsigned v = (t >= off) ? s[t - off] : 0u;
      __syncthreads();
      s[t] += v;
      __syncthreads();
    }
    if (t < NB) base[t] = s[t] - x;
    if (t == 0) base[NB] = (unsigned)E;
    __syncthreads();
  }
}

// Per-bucket finalize: thread t walks scatter-block t's segment for this bucket.
__global__ __launch_bounds__(256) void csr_finalize_kernel(
    const unsigned* __restrict__ stagedA, const unsigned char* __restrict__ stagedB,
    const unsigned* __restrict__ cntA, const unsigned* __restrict__ cntB,
    const unsigned* __restrict__ baseA,
    int* __restrict__ row_ptr, float* __restrict__ inv_dst, float* __restrict__ inv_src,
    int* __restrict__ col, int N, int E, int NB){
  __shared__ unsigned cnt[128];
  __shared__ unsigned scn[128];
  const int b = blockIdx.x, t = threadIdx.x;   // t <-> scatter block (B1==256)
  const int node0 = b << 7;
  const int nn = min(128, N - node0);
  const int chunk = (E + B1 - 1) / B1;
  const int strideB = (chunk + 3) & ~3;
  int lenb = E - t*chunk; if (lenb > chunk) lenb = chunk; if (lenb < 0) lenb = 0;

  const unsigned a0 = cntA[(size_t)t*NB + b];
  const unsigned a1 = (b < NB-1) ? cntA[(size_t)t*NB + b + 1] : (unsigned)lenb;
  const unsigned* segA = stagedA + (size_t)t*chunk;

  if (t < 128) cnt[t] = 0u;
  __syncthreads();
  for (unsigned i = a0; i < a1; i++)
    atomicAdd(&cnt[(segA[i] >> 17) & 127u], 1u);
  __syncthreads();
  unsigned mycnt = (t < 128) ? cnt[t] : 0u;
  if (t < 128) scn[t] = mycnt;
  __syncthreads();
  for (int off = 1; off < 128; off <<= 1){
    unsigned v = (t < 128 && t >= off) ? scn[t - off] : 0u;
    __syncthreads();
    if (t < 128) scn[t] += v;
    __syncthreads();
  }
  int e0 = (int)baseA[b];
  if (t < nn){
    unsigned excl = scn[t] - mycnt;
    row_ptr[node0 + t] = e0 + (int)excl;
    unsigned c = mycnt < 1u ? 1u : mycnt;
    inv_dst[node0 + t] = rsqrtf((float)c);
    cnt[t] = (unsigned)e0 + excl;   // reuse as cursor
  }
  if (b == NB - 1 && t == 0) row_ptr[N] = E;
  __syncthreads();
  for (unsigned i = a0; i < a1; i++){
    unsigned v = segA[i];
    unsigned p = atomicAdd(&cnt[(v >> 17) & 127u], 1u);
    col[p] = (int)(v & 0x1FFFFu);
  }
  // ---- job B: out-degree -> inv_src ----
  __syncthreads();
  if (t < 128) cnt[t] = 0u;
  __syncthreads();
  const unsigned b0o = cntB[(size_t)t*NB + b];
  const unsigned b1o = (b < NB-1) ? cntB[(size_t)t*NB + b + 1] : (unsigned)lenb;
  const unsigned char* segB = stagedB + (size_t)t*strideB;
  for (unsigned i = b0o; i < b1o; i++)
    atomicAdd(&cnt[segB[i]], 1u);
  __syncthreads();
  if (t < nn){
    unsigned c = cnt[t] < 1u ? 1u : cnt[t];
    inv_src[node0 + t] = rsqrtf((float)c);
  }
}

// Half-wave (32 lanes) per node; lane owns a float4. Optional per-src scale
// (layer 0: feats * inv_src[src]). Epilogue: * inv_dst[node], packed split-bf16.
template<bool SC>
__global__ __launch_bounds__(256) void csr_agg_kernel(
    const int* __restrict__ row_ptr, const int* __restrict__ col,
    const float* __restrict__ hs, const float* __restrict__ scale,
    const float* __restrict__ inv_dst, unsigned* __restrict__ aggp, int N){
  int node = (int)((blockIdx.x*256u + threadIdx.x) >> 5);
  int lane = threadIdx.x & 31;
  if (node >= N) return;
  int r0 = row_ptr[node];
  int r1 = row_ptr[node+1];
  float4 a0 = make_float4(0.f,0.f,0.f,0.f);
  float4 a1 = make_float4(0.f,0.f,0.f,0.f);
  float4 a2 = make_float4(0.f,0.f,0.f,0.f);
  float4 a3 = make_float4(0.f,0.f,0.f,0.f);
  int e = r0;
  for (; e + 3 < r1; e += 4){
    int s0 = col[e], s1 = col[e+1], s2 = col[e+2], s3 = col[e+3];
    float4 v0 = ((const float4*)(hs + (size_t)s0*128))[lane];
    float4 v1 = ((const float4*)(hs + (size_t)s1*128))[lane];
    float4 v2 = ((const float4*)(hs + (size_t)s2*128))[lane];
    float4 v3 = ((const float4*)(hs + (size_t)s3*128))[lane];
    if (SC){
      float c0 = scale[s0], c1 = scale[s1], c2 = scale[s2], c3 = scale[s3];
      v0.x*=c0; v0.y*=c0; v0.z*=c0; v0.w*=c0;
      v1.x*=c1; v1.y*=c1; v1.z*=c1; v1.w*=c1;
      v2.x*=c2; v2.y*=c2; v2.z*=c2; v2.w*=c2;
      v3.x*=c3; v3.y*=c3; v3.z*=c3; v3.w*=c3;
    }
    a0.x += v0.x; a0.y += v0.y; a0.z += v0.z; a0.w += v0.w;
    a1.x += v1.x; a1.y += v1.y; a1.z += v1.z; a1.w += v1.w;
    a2.x += v2.x; a2.y += v2.y; a2.z += v2.z; a2.w += v2.w;
    a3.x += v3.x; a3.y += v3.y; a3.z += v3.z; a3.w += v3.w;
  }
  for (; e < r1; e++){
    int s0 = col[e];
    float4 v0 = ((const float4*)(hs + (size_t)s0*128))[lane];
    if (SC){ float c0 = scale[s0]; v0.x*=c0; v0.y*=c0; v0.z*=c0; v0.w*=c0; }
    a0.x += v0.x; a0.y += v0.y; a0.z += v0.z; a0.w += v0.w;
  }
  float idst = inv_dst[node];
  float rx = ((a0.x + a1.x) + (a2.x + a3.x)) * idst;
  float ry = ((a0.y + a1.y) + (a2.y + a3.y)) * idst;
  float rz = ((a0.z + a1.z) + (a2.z + a3.z)) * idst;
  float rw = ((a0.w + a1.w) + (a2.w + a3.w)) * idst;
  uint4 p;
  p.x = pack_split(rx); p.y = pack_split(ry);
  p.z = pack_split(rz); p.w = pack_split(rw);
  ((uint4*)(aggp + (size_t)node*128))[lane] = p;
}

// Split-bf16 MFMA GEMM on packed A, B staged in LDS (padded stride 136:
// bank window 4*(mn+q)%32 -> conflict-free 8-phase ds_read_b128).
__global__ __launch_bounds__(256) void mfma_gemm_kernel(
    const unsigned* __restrict__ A,
    const __bf16* __restrict__ Whi, const __bf16* __restrict__ Wlo,
    const float* __restrict__ bias, const float* __restrict__ out_scale,
    float* __restrict__ out, int M){
  __shared__ __bf16 BhL[128*136];
  __shared__ __bf16 BlL[128*136];

  const int tid  = threadIdx.x;
  const int wv   = tid >> 6;
  const int lane = tid & 63;
  const int q    = lane >> 4;
  const int mn   = lane & 15;
  const int row0 = blockIdx.x*128 + wv*32;

  // cooperative stage: 128 rows x 16 chunks of 8 bf16, coalesced 16B moves
  for (int i = tid; i < 128*16; i += 256){
    int n = i >> 4, c = (i & 15) << 3;
    *(bf16x8*)&BhL[n*136 + c] = *(const bf16x8*)(Whi + n*128 + c);
    *(bf16x8*)&BlL[n*136 + c] = *(const bf16x8*)(Wlo + n*128 + c);
  }
  __syncthreads();

  f32x4 acc[2][8];
  #pragma unroll
  for (int mt = 0; mt < 2; mt++)
    #pragma unroll
    for (int nt = 0; nt < 8; nt++)
      acc[mt][nt] = (f32x4){0.f,0.f,0.f,0.f};

  #pragma unroll
  for (int kc = 0; kc < 4; kc++){
    bf16x8 ah[2], al[2];
    #pragma unroll
    for (int mt = 0; mt < 2; mt++){
      const unsigned* ap = A + (size_t)(row0 + mt*16 + mn)*128 + kc*32 + q*8;
      uint4 x0 = *(const uint4*)ap;
      uint4 x1 = *(const uint4*)(ap + 4);
      unsigned v[8] = {x0.x, x0.y, x0.z, x0.w, x1.x, x1.y, x1.z, x1.w};
      #pragma unroll
      for (int j = 0; j < 8; j++){
        ah[mt][j] = bits_to_bf16((unsigned short)(v[j] >> 16));
        al[mt][j] = bits_to_bf16((unsigned short)(v[j] & 0xFFFFu));
      }
    }
    #pragma unroll
    for (int nt = 0; nt < 8; nt++){
      int boff = (nt*16 + mn)*136 + kc*32 + q*8;
      bf16x8 bh = *(const bf16x8*)&BhL[boff];
      bf16x8 bl = *(const bf16x8*)&BlL[boff];
      #pragma unroll
      for (int mt = 0; mt < 2; mt++){
        acc[mt][nt] = __builtin_amdgcn_mfma_f32_16x16x32_bf16(al[mt], bh, acc[mt][nt], 0, 0, 0);
        acc[mt][nt] = __builtin_amdgcn_mfma_f32_16x16x32_bf16(ah[mt], bl, acc[mt][nt], 0, 0, 0);
        acc[mt][nt] = __builtin_amdgcn_mfma_f32_16x16x32_bf16(ah[mt], bh, acc[mt][nt], 0, 0, 0);
      }
    }
  }

  #pragma unroll
  for (int mt = 0; mt < 2; mt++){
    #pragma unroll
    for (int r = 0; r < 4; r++){
      int gm = row0 + mt*16 + q*4 + r;
      if (gm < M){
        float osc = out_scale ? out_scale[gm] : 1.f;
        #pragma unroll
        for (int nt = 0; nt < 8; nt++){
          float v = acc[mt][nt][r] + bias[nt*16 + mn];
          v = fmaxf(v, 0.f) * osc;
          out[(size_t)gm*128 + nt*16 + mn] = v;
        }
      }
    }
  }
}

// Fused head: avg-pool (8 graphs/block) + MLP 128->512->256->1, all in LDS.
__global__ __launch_bounds__(256) void head_kernel(
    const float* __restrict__ h, const int* __restrict__ gid,
    const float* __restrict__ Wm0, const float* __restrict__ bm0,
    const float* __restrict__ Wm1, const float* __restrict__ bm1,
    const float* __restrict__ Wm2, const float* __restrict__ bm2,
    float* __restrict__ out, int N, int G){
  __shared__ float embL[8][128];
  __shared__ float x1L[8][512];
  __shared__ float x2L[8][256];

  const int t = threadIdx.x;
  const int wave = t >> 6, lane = t & 63;
  const int g0 = blockIdx.x * 8;

  for (int gg = 0; gg < 2; gg++){
    int gl = wave*2 + gg;
    int g = g0 + gl;
    float ax = 0.f, ay = 0.f;
    int start = 0, end = 0;
    if (g < G){
      int lo = 0, hi = N;
      while (lo < hi){ int mid = (lo + hi) >> 1; if (gid[mid] < g) lo = mid + 1; else hi = mid; }
      start = lo;
      hi = N;
      while (lo < hi){ int mid = (lo + hi) >> 1; if (gid[mid] <= g) lo = mid + 1; else hi = mid; }
      end = lo;
      for (int n = start; n < end; n++){
        float2 v = ((const float2*)(h + (size_t)n*128))[lane];
        ax += v.x; ay += v.y;
      }
    }
    int c = end - start; if (c < 1) c = 1;
    float invc = 1.0f / (float)c;
    embL[gl][2*lane]   = ax * invc;
    embL[gl][2*lane+1] = ay * invc;
  }
  __syncthreads();

  {
    float acc[8][2];
    #pragma unroll
    for (int g = 0; g < 8; g++){ acc[g][0] = 0.f; acc[g][1] = 0.f; }
    for (int k = 0; k < 128; k++){
      float w0 = Wm0[(size_t)k*512 + t];
      float w1 = Wm0[(size_t)k*512 + t + 256];
      #pragma unroll
      for (int g = 0; g < 8; g++){
        float e = embL[g][k];
        acc[g][0] = fmaf(e, w0, acc[g][0]);
        acc[g][1] = fmaf(e, w1, acc[g][1]);
      }
    }
    float b0v = bm0[t], b1v = bm0[t + 256];
    #pragma unroll
    for (int g = 0; g < 8; g++){
      x1L[g][t]       = fmaxf(acc[g][0] + b0v, 0.f);
      x1L[g][t + 256] = fmaxf(acc[g][1] + b1v, 0.f);
    }
  }
  __syncthreads();

  {
    float acc[8];
    #pragma unroll
    for (int g = 0; g < 8; g++) acc[g] = 0.f;
    for (int k = 0; k < 512; k++){
      float w = Wm1[(size_t)k*256 + t];
      #pragma unroll
      for (int g = 0; g < 8; g++)
        acc[g] = fmaf(x1L[g][k], w, acc[g]);
    }
    float bv = bm1[t];
    #pragma unroll
    for (int g = 0; g < 8; g++)
      x2L[g][t] = fmaxf(acc[g] + bv, 0.f);
  }
  __syncthreads();

  {
    int g = t >> 5;
    int c = t & 31;
    float s = 0.f;
    for (int i = c; i < 256; i += 32)
      s = fmaf(x2L[g][i], Wm2[i], s);
    for (int off = 16; off > 0; off >>= 1) s += __shfl_down(s, off, 32);
    if (c == 0 && (g0 + g) < G) out[g0 + g] = s + bm2[0];
  }
}

extern "C" void kernel_launch(void* const* d_in, const int* in_sizes, int n_in,
                              void* d_out, int out_size, void* d_ws, size_t ws_size,
                              hipStream_t stream){
  const float* feats = (const float*)d_in[0];
  const int*   src   = (const int*)d_in[1];
  const int*   dst   = (const int*)d_in[2];
  const int*   gid   = (const int*)d_in[3];
  const float* W0 = (const float*)d_in[4];   const float* b0 = (const float*)d_in[5];
  const float* W1 = (const float*)d_in[6];   const float* b1 = (const float*)d_in[7];
  const float* W2 = (const float*)d_in[8];   const float* b2 = (const float*)d_in[9];
  const float* Wm0 = (const float*)d_in[10]; const float* bm0 = (const float*)d_in[11];
  const float* Wm1 = (const float*)d_in[12]; const float* bm1 = (const float*)d_in[13];
  const float* Wm2 = (const float*)d_in[14]; const float* bm2 = (const float*)d_in[15];
  float* out = (float*)d_out;

  const int E   = in_sizes[1];
  const int N   = in_sizes[3];
  const int G   = out_size;
  const int NB  = ceil_div(N, 128);
  const int chunk = ceil_div(E, B1);
  const int strideB = (chunk + 3) & ~3;

  char* ws = (char*)d_ws;
  size_t off = 0;
  auto carve = [&](size_t bytes) -> char* {
    off = (off + 255) & ~(size_t)255;
    char* p = ws + off; off += bytes; return p;
  };
  float* inv_src = (float*)carve((size_t)N*4);
  float* inv_dst = (float*)carve((size_t)N*4);
  int* row_ptr = (int*)carve((size_t)(N+1)*4);
  int* col     = (int*)carve((size_t)E*4);
  __bf16* Wsp = (__bf16*)carve(6*128*128*2);   // hi0,lo0,hi1,lo1,hi2,lo2
  float* hs  = (float*)carve((size_t)N*128*4);
  unsigned* aggp = (unsigned*)carve((size_t)N*128*4);

  // CSR-build temporaries alias aggp (dead until first csr_agg writes it).
  unsigned* T = (unsigned*)aggp;
  unsigned* cntA   = T;
  unsigned* cntB   = cntA + (size_t)B1*NB;
  unsigned* totals = cntB + (size_t)B1*NB;
  unsigned* baseA  = totals + 2*(size_t)NB;
  unsigned* baseB  = baseA + (NB+1);
  unsigned* stagedA = baseB + (NB+1);
  unsigned char* stagedB = (unsigned char*)(stagedA + (size_t)B1*chunk);

  scatter_count_kernel<<<B1 + WPREP_BLOCKS, 256, 0, stream>>>(
      src, dst, cntA, cntB, stagedA, stagedB, W0, W1, W2, Wsp, E, NB);
  totals_kernel<<<dim3(ceil_div(NB,256), 2), 256, 0, stream>>>(cntA, cntB, totals, NB, E);
  scan_base_kernel<<<1, NBMAX, 0, stream>>>(totals, baseA, baseB, NB, E);
  csr_finalize_kernel<<<NB, 256, 0, stream>>>(stagedA, stagedB, cntA, cntB, baseA,
                                              row_ptr, inv_dst, inv_src, col, N, E, NB);

  const int agg_blocks = ceil_div(N*32, 256);
  const int ggrid = ceil_div(N, 128);
  __bf16 *Whi0 = Wsp,            *Wlo0 = Wsp + 16384;
  __bf16 *Whi1 = Wsp + 2*16384,  *Wlo1 = Wsp + 3*16384;
  __bf16 *Whi2 = Wsp + 4*16384,  *Wlo2 = Wsp + 5*16384;
  // layer 0
  csr_agg_kernel<true><<<agg_blocks, 256, 0, stream>>>(row_ptr, col, feats, inv_src, inv_dst, aggp, N);
  mfma_gemm_kernel<<<ggrid, 256, 0, stream>>>(aggp, Whi0, Wlo0, b0, inv_src, hs, N);
  // layer 1
  csr_agg_kernel<false><<<agg_blocks, 256, 0, stream>>>(row_ptr, col, hs, nullptr, inv_dst, aggp, N);
  mfma_gemm_kernel<<<ggrid, 256, 0, stream>>>(aggp, Whi1, Wlo1, b1, inv_src, hs, N);
  // layer 2 (no out_scale)
  csr_agg_kernel<false><<<agg_blocks, 256, 0, stream>>>(row_ptr, col, hs, nullptr, inv_dst, aggp, N);
  mfma_gemm_kernel<<<ggrid, 256, 0, stream>>>(aggp, Whi2, Wlo2, b2, nullptr, hs, N);
  // fused pool + MLP head
  head_kernel<<<ceil_div(G,8), 256, 0, stream>>>(hs, gid, Wm0, bm0, Wm1, bm1, Wm2, bm2, out, N, G);
}

// Round 12
// 702.644 us; speedup vs baseline: 1.5603x; 1.0268x over previous
//
#include <hip/hip_runtime.h>

// ---------------------------------------------------------------------------
// GNN: 3x GraphConv (norm='both') + avg-pool + MLP(128->512->256->1), fp32.
// R12: csr_finalize rewritten as cooperative segmented gather (binary-search
// segment lookup -> consecutive lanes read consecutive staged elements),
// LDS sort, coalesced col writeback. R11's per-thread serial segment walk
// was ~3.2M uncoalesced 4B/1B reads ~= the hidden ~110us (26G trans/s law).
// Rest identical to R11 (721us): LDS-staged counting sort, roofline csr_agg
// (~118us x3), LDS-B mfma_gemm, fused head.
// ---------------------------------------------------------------------------

static inline int ceil_div(int a, int b){ return (a + b - 1) / b; }

#define B1 256          // scatter blocks == segments per bucket
#define NBMAX 1024      // max buckets (N <= 131072; src ids fit in 17 bits)
#define CHUNK_MAX 7168  // max edges per scatter block (E <= B1*CHUNK_MAX)
#define BUCKET_MAX 4096 // max edges per bucket (mean ~2048, 45-sigma safe)
#define WPREP_BLOCKS 192

typedef __bf16 bf16x8 __attribute__((ext_vector_type(8)));
typedef float  f32x4  __attribute__((ext_vector_type(4)));

static __device__ inline __bf16 bits_to_bf16(unsigned short u){
  union { unsigned short u; __bf16 b; } x; x.u = u; return x.b;
}
static __device__ inline unsigned short bf16_bits(__bf16 b){
  union { __bf16 b; unsigned short u; } x; x.b = b; return x.u;
}
static __device__ inline unsigned pack_split(float s){
  __bf16 h = (__bf16)s;
  __bf16 l = (__bf16)(s - (float)h);
  return ((unsigned)bf16_bits(h) << 16) | (unsigned)bf16_bits(l);
}

// One-pass bucketed counting sort, block-local staging, coalesced flush.
// Also hosts wprep on blocks >= B1 (W fp32 -> split-bf16 [n][k]).
__global__ __launch_bounds__(256) void scatter_count_kernel(
    const int* __restrict__ src, const int* __restrict__ dst,
    unsigned* __restrict__ cntA, unsigned* __restrict__ cntB,
    unsigned* __restrict__ stagedA, unsigned char* __restrict__ stagedB,
    const float* __restrict__ W0, const float* __restrict__ W1,
    const float* __restrict__ W2, __bf16* __restrict__ Wsp,
    int E, int NB){
  if (blockIdx.x >= B1){
    int gidx = (blockIdx.x - B1)*256 + threadIdx.x;    // 3*16384
    if (gidx < 3*128*128){
      int layer = gidx >> 14, idx = gidx & 16383;
      const float* W = layer == 0 ? W0 : (layer == 1 ? W1 : W2);
      int k = idx >> 7, n = idx & 127;
      float w = W[idx];
      __bf16 h = (__bf16)w;
      __bf16 l = (__bf16)(w - (float)h);
      Wsp[(size_t)layer*2*16384 + n*128 + k] = h;
      Wsp[(size_t)layer*2*16384 + 16384 + n*128 + k] = l;
    }
    return;
  }

  __shared__ unsigned la[NBMAX], lb[NBMAX];
  __shared__ unsigned tsum[256];
  __shared__ unsigned stA[CHUNK_MAX];
  __shared__ unsigned char stB[CHUNK_MAX];

  const int t = threadIdx.x;
  const int blk = blockIdx.x;
  const int chunk = (E + B1 - 1) / B1;
  const int e0 = blk * chunk, e1 = min(e0 + chunk, E);
  const int len = e1 - e0;
  const int strideB = (chunk + 3) & ~3;

  #pragma unroll
  for (int i = t; i < NBMAX; i += 256){ la[i] = 0u; lb[i] = 0u; }
  __syncthreads();
  for (int e = e0 + t; e < e1; e += 256){
    atomicAdd(&la[dst[e] >> 7], 1u);
    atomicAdd(&lb[src[e] >> 7], 1u);
  }
  __syncthreads();

  // exclusive scan of la (job A), then lb (job B); offsets also to cntA/cntB.
  for (int job = 0; job < 2; job++){
    unsigned* lx = job ? lb : la;
    unsigned* cx = job ? cntB : cntA;
    int b4 = t*4;
    unsigned v0 = lx[b4], v1 = lx[b4+1], v2 = lx[b4+2], v3 = lx[b4+3];
    unsigned s = v0+v1+v2+v3;
    tsum[t] = s;
    __syncthreads();
    for (int off = 1; off < 256; off <<= 1){
      unsigned u = (t >= off) ? tsum[t-off] : 0u;
      __syncthreads();
      tsum[t] += u;
      __syncthreads();
    }
    unsigned run = tsum[t] - s;
    unsigned o0 = run, o1 = run+v0, o2 = run+v0+v1, o3 = run+v0+v1+v2;
    lx[b4] = o0; lx[b4+1] = o1; lx[b4+2] = o2; lx[b4+3] = o3;
    if (b4   < NB) cx[(size_t)blk*NB + b4  ] = o0;
    if (b4+1 < NB) cx[(size_t)blk*NB + b4+1] = o1;
    if (b4+2 < NB) cx[(size_t)blk*NB + b4+2] = o2;
    if (b4+3 < NB) cx[(size_t)blk*NB + b4+3] = o3;
    __syncthreads();
  }

  // placement into LDS staging (la/lb now cursors).
  for (int e = e0 + t; e < e1; e += 256){
    int s = src[e], d = dst[e];
    unsigned pA = atomicAdd(&la[d >> 7], 1u);
    stA[pA] = ((unsigned)(d & 127) << 17) | (unsigned)s;
    unsigned pB = atomicAdd(&lb[s >> 7], 1u);
    stB[pB] = (unsigned char)(s & 127);
  }
  __syncthreads();

  // coalesced flush
  for (int i = t; i < len; i += 256)
    stagedA[(size_t)blk*chunk + i] = stA[i];
  int w4 = (len + 3) >> 2;
  unsigned* gB = (unsigned*)(stagedB + (size_t)blk*strideB);
  for (int i = t; i < w4; i += 256)
    gB[i] = *(unsigned*)&stB[4*i];
}

// totals[job][b] = sum over blk of per-(blk,b) counts (diff of offsets).
__global__ void totals_kernel(const unsigned* __restrict__ cntA,
                              const unsigned* __restrict__ cntB,
                              unsigned* __restrict__ totals, int NB, int E){
  int b = blockIdx.x * 256 + threadIdx.x;
  if (b >= NB) return;
  const unsigned* cx = blockIdx.y ? cntB : cntA;
  const int chunk = (E + B1 - 1) / B1;
  unsigned run = 0;
  for (int blk = 0; blk < B1; blk++){
    int lenb = E - blk*chunk; if (lenb > chunk) lenb = chunk; if (lenb < 0) lenb = 0;
    unsigned cur = cx[(size_t)blk*NB + b];
    unsigned nxt = (b < NB-1) ? cx[(size_t)blk*NB + b + 1] : (unsigned)lenb;
    run += nxt - cur;
  }
  totals[(size_t)blockIdx.y*NB + b] = run;
}

// Single-block exclusive scan of bucket totals -> baseA/baseB (each NB+1).
__global__ void scan_base_kernel(const unsigned* __restrict__ totals,
                                 unsigned* __restrict__ baseA, unsigned* __restrict__ baseB,
                                 int NB, int E){
  __shared__ unsigned s[NBMAX];
  int t = threadIdx.x;  // 1024 threads, NB <= 1024
  for (int job = 0; job < 2; job++){
    unsigned* base = job ? baseB : baseA;
    unsigned x = (t < NB) ? totals[(size_t)job*NB + t] : 0u;
    s[t] = x;
    __syncthreads();
    for (int off = 1; off < NBMAX; off <<= 1){
      unsigned v = (t >= off) ? s[t - off] : 0u;
      __syncthreads();
      s[t] += v;
      __syncthreads();
    }
    if (t < NB) base[t] = s[t] - x;
    if (t == 0) base[NB] = (unsigned)E;
    __syncthreads();
  }
}

// Per-bucket finalize, cooperative segmented gather version.
// Segment s of bucket b = stagedA[s*chunk + cntA[s][b] .. cntA[s][b+1]).
// Threads process bucket elements by global index; binary search (LDS) finds
// the owning segment -> consecutive lanes read consecutive staged elements.
__global__ __launch_bounds__(256) void csr_finalize_kernel(
    const unsigned* __restrict__ stagedA, const unsigned char* __restrict__ stagedB,
    const unsigned* __restrict__ cntA, const unsigned* __restrict__ cntB,
    const unsigned* __restrict__ baseA,
    int* __restrict__ row_ptr, float* __restrict__ inv_dst, float* __restrict__ inv_src,
    int* __restrict__ col, int N, int E, int NB){
  __shared__ unsigned offs[256];
  __shared__ unsigned segbase[257];
  __shared__ unsigned tsum[256];
  __shared__ unsigned edge[BUCKET_MAX];
  __shared__ unsigned sorted[BUCKET_MAX];
  __shared__ unsigned cnt[128];
  __shared__ unsigned scn[128];

  const int b = blockIdx.x, t = threadIdx.x;
  const int node0 = b << 7;
  const int nn = min(128, N - node0);
  const int chunk = (E + B1 - 1) / B1;
  const int strideB = (chunk + 3) & ~3;
  int lenb_t = E - t*chunk; if (lenb_t > chunk) lenb_t = chunk; if (lenb_t < 0) lenb_t = 0;

  // ================= job A: CSR =================
  {
    unsigned o0 = cntA[(size_t)t*NB + b];
    unsigned o1 = (b < NB-1) ? cntA[(size_t)t*NB + b + 1] : (unsigned)lenb_t;
    unsigned len = o1 - o0;
    offs[t] = o0;
    tsum[t] = len;
    __syncthreads();
    for (int off = 1; off < 256; off <<= 1){
      unsigned u = (t >= off) ? tsum[t-off] : 0u;
      __syncthreads();
      tsum[t] += u;
      __syncthreads();
    }
    segbase[t] = tsum[t] - len;
    if (t == 255) segbase[256] = tsum[255];
    __syncthreads();
    int bucketlen = (int)segbase[256];

    // gather: consecutive idx -> consecutive elements within a segment
    for (int idx = t; idx < bucketlen; idx += 256){
      int lo = 0, hi = 255;
      while (lo < hi){ int m = (lo + hi + 1) >> 1; if (segbase[m] <= (unsigned)idx) lo = m; else hi = m - 1; }
      edge[idx] = stagedA[(size_t)lo*chunk + offs[lo] + ((unsigned)idx - segbase[lo])];
    }
    if (t < 128) cnt[t] = 0u;
    __syncthreads();
    for (int idx = t; idx < bucketlen; idx += 256)
      atomicAdd(&cnt[(edge[idx] >> 17) & 127u], 1u);
    __syncthreads();
    unsigned mycnt = (t < 128) ? cnt[t] : 0u;
    if (t < 128) scn[t] = mycnt;
    __syncthreads();
    for (int off = 1; off < 128; off <<= 1){
      unsigned v = (t < 128 && t >= off) ? scn[t - off] : 0u;
      __syncthreads();
      if (t < 128) scn[t] += v;
      __syncthreads();
    }
    int e0 = (int)baseA[b];
    if (t < nn){
      unsigned excl = scn[t] - mycnt;
      row_ptr[node0 + t] = e0 + (int)excl;
      unsigned c = mycnt < 1u ? 1u : mycnt;
      inv_dst[node0 + t] = rsqrtf((float)c);
      cnt[t] = excl;               // bucket-local cursor
    }
    if (b == NB - 1 && t == 0) row_ptr[N] = E;
    __syncthreads();
    // LDS scatter (sort by node), then coalesced writeback
    for (int idx = t; idx < bucketlen; idx += 256){
      unsigned v = edge[idx];
      unsigned p = atomicAdd(&cnt[(v >> 17) & 127u], 1u);
      sorted[p] = v & 0x1FFFFu;
    }
    __syncthreads();
    for (int idx = t; idx < bucketlen; idx += 256)
      col[e0 + idx] = (int)sorted[idx];
  }

  // ================= job B: out-degree -> inv_src =================
  __syncthreads();
  {
    unsigned o0 = cntB[(size_t)t*NB + b];
    unsigned o1 = (b < NB-1) ? cntB[(size_t)t*NB + b + 1] : (unsigned)lenb_t;
    unsigned len = o1 - o0;
    offs[t] = o0;
    tsum[t] = len;
    __syncthreads();
    for (int off = 1; off < 256; off <<= 1){
      unsigned u = (t >= off) ? tsum[t-off] : 0u;
      __syncthreads();
      tsum[t] += u;
      __syncthreads();
    }
    segbase[t] = tsum[t] - len;
    if (t == 255) segbase[256] = tsum[255];
    if (t < 128) cnt[t] = 0u;
    __syncthreads();
    int bucketlen = (int)segbase[256];
    unsigned char* edgeB = (unsigned char*)edge;
    for (int idx = t; idx < bucketlen; idx += 256){
      int lo = 0, hi = 255;
      while (lo < hi){ int m = (lo + hi + 1) >> 1; if (segbase[m] <= (unsigned)idx) lo = m; else hi = m - 1; }
      edgeB[idx] = stagedB[(size_t)lo*strideB + offs[lo] + ((unsigned)idx - segbase[lo])];
    }
    __syncthreads();
    for (int idx = t; idx < bucketlen; idx += 256)
      atomicAdd(&cnt[edgeB[idx]], 1u);
    __syncthreads();
    if (t < nn){
      unsigned c = cnt[t] < 1u ? 1u : cnt[t];
      inv_src[node0 + t] = rsqrtf((float)c);
    }
  }
}

// Half-wave (32 lanes) per node; lane owns a float4. Optional per-src scale
// (layer 0: feats * inv_src[src]). Epilogue: * inv_dst[node], packed split-bf16.
template<bool SC>
__global__ __launch_bounds__(256) void csr_agg_kernel(
    const int* __restrict__ row_ptr, const int* __restrict__ col,
    const float* __restrict__ hs, const float* __restrict__ scale,
    const float* __restrict__ inv_dst, unsigned* __restrict__ aggp, int N){
  int node = (int)((blockIdx.x*256u + threadIdx.x) >> 5);
  int lane = threadIdx.x & 31;
  if (node >= N) return;
  int r0 = row_ptr[node];
  int r1 = row_ptr[node+1];
  float4 a0 = make_float4(0.f,0.f,0.f,0.f);
  float4 a1 = make_float4(0.f,0.f,0.f,0.f);
  float4 a2 = make_float4(0.f,0.f,0.f,0.f);
  float4 a3 = make_float4(0.f,0.f,0.f,0.f);
  int e = r0;
  for (; e + 3 < r1; e += 4){
    int s0 = col[e], s1 = col[e+1], s2 = col[e+2], s3 = col[e+3];
    float4 v0 = ((const float4*)(hs + (size_t)s0*128))[lane];
    float4 v1 = ((const float4*)(hs + (size_t)s1*128))[lane];
    float4 v2 = ((const float4*)(hs + (size_t)s2*128))[lane];
    float4 v3 = ((const float4*)(hs + (size_t)s3*128))[lane];
    if (SC){
      float c0 = scale[s0], c1 = scale[s1], c2 = scale[s2], c3 = scale[s3];
      v0.x*=c0; v0.y*=c0; v0.z*=c0; v0.w*=c0;
      v1.x*=c1; v1.y*=c1; v1.z*=c1; v1.w*=c1;
      v2.x*=c2; v2.y*=c2; v2.z*=c2; v2.w*=c2;
      v3.x*=c3; v3.y*=c3; v3.z*=c3; v3.w*=c3;
    }
    a0.x += v0.x; a0.y += v0.y; a0.z += v0.z; a0.w += v0.w;
    a1.x += v1.x; a1.y += v1.y; a1.z += v1.z; a1.w += v1.w;
    a2.x += v2.x; a2.y += v2.y; a2.z += v2.z; a2.w += v2.w;
    a3.x += v3.x; a3.y += v3.y; a3.z += v3.z; a3.w += v3.w;
  }
  for (; e < r1; e++){
    int s0 = col[e];
    float4 v0 = ((const float4*)(hs + (size_t)s0*128))[lane];
    if (SC){ float c0 = scale[s0]; v0.x*=c0; v0.y*=c0; v0.z*=c0; v0.w*=c0; }
    a0.x += v0.x; a0.y += v0.y; a0.z += v0.z; a0.w += v0.w;
  }
  float idst = inv_dst[node];
  float rx = ((a0.x + a1.x) + (a2.x + a3.x)) * idst;
  float ry = ((a0.y + a1.y) + (a2.y + a3.y)) * idst;
  float rz = ((a0.z + a1.z) + (a2.z + a3.z)) * idst;
  float rw = ((a0.w + a1.w) + (a2.w + a3.w)) * idst;
  uint4 p;
  p.x = pack_split(rx); p.y = pack_split(ry);
  p.z = pack_split(rz); p.w = pack_split(rw);
  ((uint4*)(aggp + (size_t)node*128))[lane] = p;
}

// Split-bf16 MFMA GEMM on packed A, B staged in LDS (padded stride 136).
__global__ __launch_bounds__(256) void mfma_gemm_kernel(
    const unsigned* __restrict__ A,
    const __bf16* __restrict__ Whi, const __bf16* __restrict__ Wlo,
    const float* __restrict__ bias, const float* __restrict__ out_scale,
    float* __restrict__ out, int M){
  __shared__ __bf16 BhL[128*136];
  __shared__ __bf16 BlL[128*136];

  const int tid  = threadIdx.x;
  const int wv   = tid >> 6;
  const int lane = tid & 63;
  const int q    = lane >> 4;
  const int mn   = lane & 15;
  const int row0 = blockIdx.x*128 + wv*32;

  for (int i = tid; i < 128*16; i += 256){
    int n = i >> 4, c = (i & 15) << 3;
    *(bf16x8*)&BhL[n*136 + c] = *(const bf16x8*)(Whi + n*128 + c);
    *(bf16x8*)&BlL[n*136 + c] = *(const bf16x8*)(Wlo + n*128 + c);
  }
  __syncthreads();

  f32x4 acc[2][8];
  #pragma unroll
  for (int mt = 0; mt < 2; mt++)
    #pragma unroll
    for (int nt = 0; nt < 8; nt++)
      acc[mt][nt] = (f32x4){0.f,0.f,0.f,0.f};

  #pragma unroll
  for (int kc = 0; kc < 4; kc++){
    bf16x8 ah[2], al[2];
    #pragma unroll
    for (int mt = 0; mt < 2; mt++){
      const unsigned* ap = A + (size_t)(row0 + mt*16 + mn)*128 + kc*32 + q*8;
      uint4 x0 = *(const uint4*)ap;
      uint4 x1 = *(const uint4*)(ap + 4);
      unsigned v[8] = {x0.x, x0.y, x0.z, x0.w, x1.x, x1.y, x1.z, x1.w};
      #pragma unroll
      for (int j = 0; j < 8; j++){
        ah[mt][j] = bits_to_bf16((unsigned short)(v[j] >> 16));
        al[mt][j] = bits_to_bf16((unsigned short)(v[j] & 0xFFFFu));
      }
    }
    #pragma unroll
    for (int nt = 0; nt < 8; nt++){
      int boff = (nt*16 + mn)*136 + kc*32 + q*8;
      bf16x8 bh = *(const bf16x8*)&BhL[boff];
      bf16x8 bl = *(const bf16x8*)&BlL[boff];
      #pragma unroll
      for (int mt = 0; mt < 2; mt++){
        acc[mt][nt] = __builtin_amdgcn_mfma_f32_16x16x32_bf16(al[mt], bh, acc[mt][nt], 0, 0, 0);
        acc[mt][nt] = __builtin_amdgcn_mfma_f32_16x16x32_bf16(ah[mt], bl, acc[mt][nt], 0, 0, 0);
        acc[mt][nt] = __builtin_amdgcn_mfma_f32_16x16x32_bf16(ah[mt], bh, acc[mt][nt], 0, 0, 0);
      }
    }
  }

  #pragma unroll
  for (int mt = 0; mt < 2; mt++){
    #pragma unroll
    for (int r = 0; r < 4; r++){
      int gm = row0 + mt*16 + q*4 + r;
      if (gm < M){
        float osc = out_scale ? out_scale[gm] : 1.f;
        #pragma unroll
        for (int nt = 0; nt < 8; nt++){
          float v = acc[mt][nt][r] + bias[nt*16 + mn];
          v = fmaxf(v, 0.f) * osc;
          out[(size_t)gm*128 + nt*16 + mn] = v;
        }
      }
    }
  }
}

// Fused head: avg-pool (8 graphs/block) + MLP 128->512->256->1, all in LDS.
__global__ __launch_bounds__(256) void head_kernel(
    const float* __restrict__ h, const int* __restrict__ gid,
    const float* __restrict__ Wm0, const float* __restrict__ bm0,
    const float* __restrict__ Wm1, const float* __restrict__ bm1,
    const float* __restrict__ Wm2, const float* __restrict__ bm2,
    float* __restrict__ out, int N, int G){
  __shared__ float embL[8][128];
  __shared__ float x1L[8][512];
  __shared__ float x2L[8][256];

  const int t = threadIdx.x;
  const int wave = t >> 6, lane = t & 63;
  const int g0 = blockIdx.x * 8;

  for (int gg = 0; gg < 2; gg++){
    int gl = wave*2 + gg;
    int g = g0 + gl;
    float ax = 0.f, ay = 0.f;
    int start = 0, end = 0;
    if (g < G){
      int lo = 0, hi = N;
      while (lo < hi){ int mid = (lo + hi) >> 1; if (gid[mid] < g) lo = mid + 1; else hi = mid; }
      start = lo;
      hi = N;
      while (lo < hi){ int mid = (lo + hi) >> 1; if (gid[mid] <= g) lo = mid + 1; else hi = mid; }
      end = lo;
      for (int n = start; n < end; n++){
        float2 v = ((const float2*)(h + (size_t)n*128))[lane];
        ax += v.x; ay += v.y;
      }
    }
    int c = end - start; if (c < 1) c = 1;
    float invc = 1.0f / (float)c;
    embL[gl][2*lane]   = ax * invc;
    embL[gl][2*lane+1] = ay * invc;
  }
  __syncthreads();

  {
    float acc[8][2];
    #pragma unroll
    for (int g = 0; g < 8; g++){ acc[g][0] = 0.f; acc[g][1] = 0.f; }
    for (int k = 0; k < 128; k++){
      float w0 = Wm0[(size_t)k*512 + t];
      float w1 = Wm0[(size_t)k*512 + t + 256];
      #pragma unroll
      for (int g = 0; g < 8; g++){
        float e = embL[g][k];
        acc[g][0] = fmaf(e, w0, acc[g][0]);
        acc[g][1] = fmaf(e, w1, acc[g][1]);
      }
    }
    float b0v = bm0[t], b1v = bm0[t + 256];
    #pragma unroll
    for (int g = 0; g < 8; g++){
      x1L[g][t]       = fmaxf(acc[g][0] + b0v, 0.f);
      x1L[g][t + 256] = fmaxf(acc[g][1] + b1v, 0.f);
    }
  }
  __syncthreads();

  {
    float acc[8];
    #pragma unroll
    for (int g = 0; g < 8; g++) acc[g] = 0.f;
    for (int k = 0; k < 512; k++){
      float w = Wm1[(size_t)k*256 + t];
      #pragma unroll
      for (int g = 0; g < 8; g++)
        acc[g] = fmaf(x1L[g][k], w, acc[g]);
    }
    float bv = bm1[t];
    #pragma unroll
    for (int g = 0; g < 8; g++)
      x2L[g][t] = fmaxf(acc[g] + bv, 0.f);
  }
  __syncthreads();

  {
    int g = t >> 5;
    int c = t & 31;
    float s = 0.f;
    for (int i = c; i < 256; i += 32)
      s = fmaf(x2L[g][i], Wm2[i], s);
    for (int off = 16; off > 0; off >>= 1) s += __shfl_down(s, off, 32);
    if (c == 0 && (g0 + g) < G) out[g0 + g] = s + bm2[0];
  }
}

extern "C" void kernel_launch(void* const* d_in, const int* in_sizes, int n_in,
                              void* d_out, int out_size, void* d_ws, size_t ws_size,
                              hipStream_t stream){
  const float* feats = (const float*)d_in[0];
  const int*   src   = (const int*)d_in[1];
  const int*   dst   = (const int*)d_in[2];
  const int*   gid   = (const int*)d_in[3];
  const float* W0 = (const float*)d_in[4];   const float* b0 = (const float*)d_in[5];
  const float* W1 = (const float*)d_in[6];   const float* b1 = (const float*)d_in[7];
  const float* W2 = (const float*)d_in[8];   const float* b2 = (const float*)d_in[9];
  const float* Wm0 = (const float*)d_in[10]; const float* bm0 = (const float*)d_in[11];
  const float* Wm1 = (const float*)d_in[12]; const float* bm1 = (const float*)d_in[13];
  const float* Wm2 = (const float*)d_in[14]; const float* bm2 = (const float*)d_in[15];
  float* out = (float*)d_out;

  const int E   = in_sizes[1];
  const int N   = in_sizes[3];
  const int G   = out_size;
  const int NB  = ceil_div(N, 128);
  const int chunk = ceil_div(E, B1);
  const int strideB = (chunk + 3) & ~3;

  char* ws = (char*)d_ws;
  size_t off = 0;
  auto carve = [&](size_t bytes) -> char* {
    off = (off + 255) & ~(size_t)255;
    char* p = ws + off; off += bytes; return p;
  };
  float* inv_src = (float*)carve((size_t)N*4);
  float* inv_dst = (float*)carve((size_t)N*4);
  int* row_ptr = (int*)carve((size_t)(N+1)*4);
  int* col     = (int*)carve((size_t)E*4);
  __bf16* Wsp = (__bf16*)carve(6*128*128*2);   // hi0,lo0,hi1,lo1,hi2,lo2
  float* hs  = (float*)carve((size_t)N*128*4);
  unsigned* aggp = (unsigned*)carve((size_t)N*128*4);

  // CSR-build temporaries alias aggp (dead until first csr_agg writes it).
  unsigned* T = (unsigned*)aggp;
  unsigned* cntA   = T;
  unsigned* cntB   = cntA + (size_t)B1*NB;
  unsigned* totals = cntB + (size_t)B1*NB;
  unsigned* baseA  = totals + 2*(size_t)NB;
  unsigned* baseB  = baseA + (NB+1);
  unsigned* stagedA = baseB + (NB+1);
  unsigned char* stagedB = (unsigned char*)(stagedA + (size_t)B1*chunk);

  scatter_count_kernel<<<B1 + WPREP_BLOCKS, 256, 0, stream>>>(
      src, dst, cntA, cntB, stagedA, stagedB, W0, W1, W2, Wsp, E, NB);
  totals_kernel<<<dim3(ceil_div(NB,256), 2), 256, 0, stream>>>(cntA, cntB, totals, NB, E);
  scan_base_kernel<<<1, NBMAX, 0, stream>>>(totals, baseA, baseB, NB, E);
  csr_finalize_kernel<<<NB, 256, 0, stream>>>(stagedA, stagedB, cntA, cntB, baseA,
                                              row_ptr, inv_dst, inv_src, col, N, E, NB);

  const int agg_blocks = ceil_div(N*32, 256);
  const int ggrid = ceil_div(N, 128);
  __bf16 *Whi0 = Wsp,            *Wlo0 = Wsp + 16384;
  __bf16 *Whi1 = Wsp + 2*16384,  *Wlo1 = Wsp + 3*16384;
  __bf16 *Whi2 = Wsp + 4*16384,  *Wlo2 = Wsp + 5*16384;
  // layer 0
  csr_agg_kernel<true><<<agg_blocks, 256, 0, stream>>>(row_ptr, col, feats, inv_src, inv_dst, aggp, N);
  mfma_gemm_kernel<<<ggrid, 256, 0, stream>>>(aggp, Whi0, Wlo0, b0, inv_src, hs, N);
  // layer 1
  csr_agg_kernel<false><<<agg_blocks, 256, 0, stream>>>(row_ptr, col, hs, nullptr, inv_dst, aggp, N);
  mfma_gemm_kernel<<<ggrid, 256, 0, stream>>>(aggp, Whi1, Wlo1, b1, inv_src, hs, N);
  // layer 2 (no out_scale)
  csr_agg_kernel<false><<<agg_blocks, 256, 0, stream>>>(row_ptr, col, hs, nullptr, inv_dst, aggp, N);
  mfma_gemm_kernel<<<ggrid, 256, 0, stream>>>(aggp, Whi2, Wlo2, b2, nullptr, hs, N);
  // fused pool + MLP head
  head_kernel<<<ceil_div(G,8), 256, 0, stream>>>(hs, gid, Wm0, bm0, Wm1, bm1, Wm2, bm2, out, N, G);
}

// Round 13
// 696.718 us; speedup vs baseline: 1.5736x; 1.0085x over previous
//
#include <hip/hip_runtime.h>

// ---------------------------------------------------------------------------
// GNN: 3x GraphConv (norm='both') + avg-pool + MLP(128->512->256->1), fp32.
// R13: mfma_gemm stages B per-kc slice (20.5 KB LDS vs 69.6 KB) -> ~6-7
// blocks/CU instead of 2 (R11/R12 ran 782 blocks in 2 quantized rounds at
// 8 waves/CU). Same global traffic, same MFMA order (bit-identical).
// csr_agg confirmed transaction-bound at ~26G lines/s, within ~10% of its
// structural duplication floor -> untouched. Rest identical to R12 (703us).
// ---------------------------------------------------------------------------

static inline int ceil_div(int a, int b){ return (a + b - 1) / b; }

#define B1 256          // scatter blocks == segments per bucket
#define NBMAX 1024      // max buckets (N <= 131072; src ids fit in 17 bits)
#define CHUNK_MAX 7168  // max edges per scatter block (E <= B1*CHUNK_MAX)
#define BUCKET_MAX 4096 // max edges per bucket (mean ~2048)
#define WPREP_BLOCKS 192

typedef __bf16 bf16x8 __attribute__((ext_vector_type(8)));
typedef float  f32x4  __attribute__((ext_vector_type(4)));

static __device__ inline __bf16 bits_to_bf16(unsigned short u){
  union { unsigned short u; __bf16 b; } x; x.u = u; return x.b;
}
static __device__ inline unsigned short bf16_bits(__bf16 b){
  union { __bf16 b; unsigned short u; } x; x.b = b; return x.u;
}
static __device__ inline unsigned pack_split(float s){
  __bf16 h = (__bf16)s;
  __bf16 l = (__bf16)(s - (float)h);
  return ((unsigned)bf16_bits(h) << 16) | (unsigned)bf16_bits(l);
}

// One-pass bucketed counting sort, block-local staging, coalesced flush.
// Also hosts wprep on blocks >= B1 (W fp32 -> split-bf16 [n][k]).
__global__ __launch_bounds__(256) void scatter_count_kernel(
    const int* __restrict__ src, const int* __restrict__ dst,
    unsigned* __restrict__ cntA, unsigned* __restrict__ cntB,
    unsigned* __restrict__ stagedA, unsigned char* __restrict__ stagedB,
    const float* __restrict__ W0, const float* __restrict__ W1,
    const float* __restrict__ W2, __bf16* __restrict__ Wsp,
    int E, int NB){
  if (blockIdx.x >= B1){
    int gidx = (blockIdx.x - B1)*256 + threadIdx.x;    // 3*16384
    if (gidx < 3*128*128){
      int layer = gidx >> 14, idx = gidx & 16383;
      const float* W = layer == 0 ? W0 : (layer == 1 ? W1 : W2);
      int k = idx >> 7, n = idx & 127;
      float w = W[idx];
      __bf16 h = (__bf16)w;
      __bf16 l = (__bf16)(w - (float)h);
      Wsp[(size_t)layer*2*16384 + n*128 + k] = h;
      Wsp[(size_t)layer*2*16384 + 16384 + n*128 + k] = l;
    }
    return;
  }

  __shared__ unsigned la[NBMAX], lb[NBMAX];
  __shared__ unsigned tsum[256];
  __shared__ unsigned stA[CHUNK_MAX];
  __shared__ unsigned char stB[CHUNK_MAX];

  const int t = threadIdx.x;
  const int blk = blockIdx.x;
  const int chunk = (E + B1 - 1) / B1;
  const int e0 = blk * chunk, e1 = min(e0 + chunk, E);
  const int len = e1 - e0;
  const int strideB = (chunk + 3) & ~3;

  #pragma unroll
  for (int i = t; i < NBMAX; i += 256){ la[i] = 0u; lb[i] = 0u; }
  __syncthreads();
  for (int e = e0 + t; e < e1; e += 256){
    atomicAdd(&la[dst[e] >> 7], 1u);
    atomicAdd(&lb[src[e] >> 7], 1u);
  }
  __syncthreads();

  for (int job = 0; job < 2; job++){
    unsigned* lx = job ? lb : la;
    unsigned* cx = job ? cntB : cntA;
    int b4 = t*4;
    unsigned v0 = lx[b4], v1 = lx[b4+1], v2 = lx[b4+2], v3 = lx[b4+3];
    unsigned s = v0+v1+v2+v3;
    tsum[t] = s;
    __syncthreads();
    for (int off = 1; off < 256; off <<= 1){
      unsigned u = (t >= off) ? tsum[t-off] : 0u;
      __syncthreads();
      tsum[t] += u;
      __syncthreads();
    }
    unsigned run = tsum[t] - s;
    unsigned o0 = run, o1 = run+v0, o2 = run+v0+v1, o3 = run+v0+v1+v2;
    lx[b4] = o0; lx[b4+1] = o1; lx[b4+2] = o2; lx[b4+3] = o3;
    if (b4   < NB) cx[(size_t)blk*NB + b4  ] = o0;
    if (b4+1 < NB) cx[(size_t)blk*NB + b4+1] = o1;
    if (b4+2 < NB) cx[(size_t)blk*NB + b4+2] = o2;
    if (b4+3 < NB) cx[(size_t)blk*NB + b4+3] = o3;
    __syncthreads();
  }

  for (int e = e0 + t; e < e1; e += 256){
    int s = src[e], d = dst[e];
    unsigned pA = atomicAdd(&la[d >> 7], 1u);
    stA[pA] = ((unsigned)(d & 127) << 17) | (unsigned)s;
    unsigned pB = atomicAdd(&lb[s >> 7], 1u);
    stB[pB] = (unsigned char)(s & 127);
  }
  __syncthreads();

  for (int i = t; i < len; i += 256)
    stagedA[(size_t)blk*chunk + i] = stA[i];
  int w4 = (len + 3) >> 2;
  unsigned* gB = (unsigned*)(stagedB + (size_t)blk*strideB);
  for (int i = t; i < w4; i += 256)
    gB[i] = *(unsigned*)&stB[4*i];
}

// totals[job][b] = sum over blk of per-(blk,b) counts (diff of offsets).
__global__ void totals_kernel(const unsigned* __restrict__ cntA,
                              const unsigned* __restrict__ cntB,
                              unsigned* __restrict__ totals, int NB, int E){
  int b = blockIdx.x * 256 + threadIdx.x;
  if (b >= NB) return;
  const unsigned* cx = blockIdx.y ? cntB : cntA;
  const int chunk = (E + B1 - 1) / B1;
  unsigned run = 0;
  for (int blk = 0; blk < B1; blk++){
    int lenb = E - blk*chunk; if (lenb > chunk) lenb = chunk; if (lenb < 0) lenb = 0;
    unsigned cur = cx[(size_t)blk*NB + b];
    unsigned nxt = (b < NB-1) ? cx[(size_t)blk*NB + b + 1] : (unsigned)lenb;
    run += nxt - cur;
  }
  totals[(size_t)blockIdx.y*NB + b] = run;
}

// Single-block exclusive scan of bucket totals -> baseA/baseB (each NB+1).
__global__ void scan_base_kernel(const unsigned* __restrict__ totals,
                                 unsigned* __restrict__ baseA, unsigned* __restrict__ baseB,
                                 int NB, int E){
  __shared__ unsigned s[NBMAX];
  int t = threadIdx.x;  // 1024 threads, NB <= 1024
  for (int job = 0; job < 2; job++){
    unsigned* base = job ? baseB : baseA;
    unsigned x = (t < NB) ? totals[(size_t)job*NB + t] : 0u;
    s[t] = x;
    __syncthreads();
    for (int off = 1; off < NBMAX; off <<= 1){
      unsigned v = (t >= off) ? s[t - off] : 0u;
      __syncthreads();
      s[t] += v;
      __syncthreads();
    }
    if (t < NB) base[t] = s[t] - x;
    if (t == 0) base[NB] = (unsigned)E;
    __syncthreads();
  }
}

// Per-bucket finalize, cooperative segmented gather (R12).
__global__ __launch_bounds__(256) void csr_finalize_kernel(
    const unsigned* __restrict__ stagedA, const unsigned char* __restrict__ stagedB,
    const unsigned* __restrict__ cntA, const unsigned* __restrict__ cntB,
    const unsigned* __restrict__ baseA,
    int* __restrict__ row_ptr, float* __restrict__ inv_dst, float* __restrict__ inv_src,
    int* __restrict__ col, int N, int E, int NB){
  __shared__ unsigned offs[256];
  __shared__ unsigned segbase[257];
  __shared__ unsigned tsum[256];
  __shared__ unsigned edge[BUCKET_MAX];
  __shared__ unsigned sorted[BUCKET_MAX];
  __shared__ unsigned cnt[128];
  __shared__ unsigned scn[128];

  const int b = blockIdx.x, t = threadIdx.x;
  const int node0 = b << 7;
  const int nn = min(128, N - node0);
  const int chunk = (E + B1 - 1) / B1;
  const int strideB = (chunk + 3) & ~3;
  int lenb_t = E - t*chunk; if (lenb_t > chunk) lenb_t = chunk; if (lenb_t < 0) lenb_t = 0;

  // ================= job A: CSR =================
  {
    unsigned o0 = cntA[(size_t)t*NB + b];
    unsigned o1 = (b < NB-1) ? cntA[(size_t)t*NB + b + 1] : (unsigned)lenb_t;
    unsigned len = o1 - o0;
    offs[t] = o0;
    tsum[t] = len;
    __syncthreads();
    for (int off = 1; off < 256; off <<= 1){
      unsigned u = (t >= off) ? tsum[t-off] : 0u;
      __syncthreads();
      tsum[t] += u;
      __syncthreads();
    }
    segbase[t] = tsum[t] - len;
    if (t == 255) segbase[256] = tsum[255];
    __syncthreads();
    int bucketlen = (int)segbase[256];

    for (int idx = t; idx < bucketlen; idx += 256){
      int lo = 0, hi = 255;
      while (lo < hi){ int m = (lo + hi + 1) >> 1; if (segbase[m] <= (unsigned)idx) lo = m; else hi = m - 1; }
      edge[idx] = stagedA[(size_t)lo*chunk + offs[lo] + ((unsigned)idx - segbase[lo])];
    }
    if (t < 128) cnt[t] = 0u;
    __syncthreads();
    for (int idx = t; idx < bucketlen; idx += 256)
      atomicAdd(&cnt[(edge[idx] >> 17) & 127u], 1u);
    __syncthreads();
    unsigned mycnt = (t < 128) ? cnt[t] : 0u;
    if (t < 128) scn[t] = mycnt;
    __syncthreads();
    for (int off = 1; off < 128; off <<= 1){
      unsigned v = (t < 128 && t >= off) ? scn[t - off] : 0u;
      __syncthreads();
      if (t < 128) scn[t] += v;
      __syncthreads();
    }
    int e0 = (int)baseA[b];
    if (t < nn){
      unsigned excl = scn[t] - mycnt;
      row_ptr[node0 + t] = e0 + (int)excl;
      unsigned c = mycnt < 1u ? 1u : mycnt;
      inv_dst[node0 + t] = rsqrtf((float)c);
      cnt[t] = excl;               // bucket-local cursor
    }
    if (b == NB - 1 && t == 0) row_ptr[N] = E;
    __syncthreads();
    for (int idx = t; idx < bucketlen; idx += 256){
      unsigned v = edge[idx];
      unsigned p = atomicAdd(&cnt[(v >> 17) & 127u], 1u);
      sorted[p] = v & 0x1FFFFu;
    }
    __syncthreads();
    for (int idx = t; idx < bucketlen; idx += 256)
      col[e0 + idx] = (int)sorted[idx];
  }

  // ================= job B: out-degree -> inv_src =================
  __syncthreads();
  {
    unsigned o0 = cntB[(size_t)t*NB + b];
    unsigned o1 = (b < NB-1) ? cntB[(size_t)t*NB + b + 1] : (unsigned)lenb_t;
    unsigned len = o1 - o0;
    offs[t] = o0;
    tsum[t] = len;
    __syncthreads();
    for (int off = 1; off < 256; off <<= 1){
      unsigned u = (t >= off) ? tsum[t-off] : 0u;
      __syncthreads();
      tsum[t] += u;
      __syncthreads();
    }
    segbase[t] = tsum[t] - len;
    if (t == 255) segbase[256] = tsum[255];
    if (t < 128) cnt[t] = 0u;
    __syncthreads();
    int bucketlen = (int)segbase[256];
    unsigned char* edgeB = (unsigned char*)edge;
    for (int idx = t; idx < bucketlen; idx += 256){
      int lo = 0, hi = 255;
      while (lo < hi){ int m = (lo + hi + 1) >> 1; if (segbase[m] <= (unsigned)idx) lo = m; else hi = m - 1; }
      edgeB[idx] = stagedB[(size_t)lo*strideB + offs[lo] + ((unsigned)idx - segbase[lo])];
    }
    __syncthreads();
    for (int idx = t; idx < bucketlen; idx += 256)
      atomicAdd(&cnt[edgeB[idx]], 1u);
    __syncthreads();
    if (t < nn){
      unsigned c = cnt[t] < 1u ? 1u : cnt[t];
      inv_src[node0 + t] = rsqrtf((float)c);
    }
  }
}

// Half-wave (32 lanes) per node; lane owns a float4. Optional per-src scale
// (layer 0: feats * inv_src[src]). Epilogue: * inv_dst[node], packed split-bf16.
template<bool SC>
__global__ __launch_bounds__(256) void csr_agg_kernel(
    const int* __restrict__ row_ptr, const int* __restrict__ col,
    const float* __restrict__ hs, const float* __restrict__ scale,
    const float* __restrict__ inv_dst, unsigned* __restrict__ aggp, int N){
  int node = (int)((blockIdx.x*256u + threadIdx.x) >> 5);
  int lane = threadIdx.x & 31;
  if (node >= N) return;
  int r0 = row_ptr[node];
  int r1 = row_ptr[node+1];
  float4 a0 = make_float4(0.f,0.f,0.f,0.f);
  float4 a1 = make_float4(0.f,0.f,0.f,0.f);
  float4 a2 = make_float4(0.f,0.f,0.f,0.f);
  float4 a3 = make_float4(0.f,0.f,0.f,0.f);
  int e = r0;
  for (; e + 3 < r1; e += 4){
    int s0 = col[e], s1 = col[e+1], s2 = col[e+2], s3 = col[e+3];
    float4 v0 = ((const float4*)(hs + (size_t)s0*128))[lane];
    float4 v1 = ((const float4*)(hs + (size_t)s1*128))[lane];
    float4 v2 = ((const float4*)(hs + (size_t)s2*128))[lane];
    float4 v3 = ((const float4*)(hs + (size_t)s3*128))[lane];
    if (SC){
      float c0 = scale[s0], c1 = scale[s1], c2 = scale[s2], c3 = scale[s3];
      v0.x*=c0; v0.y*=c0; v0.z*=c0; v0.w*=c0;
      v1.x*=c1; v1.y*=c1; v1.z*=c1; v1.w*=c1;
      v2.x*=c2; v2.y*=c2; v2.z*=c2; v2.w*=c2;
      v3.x*=c3; v3.y*=c3; v3.z*=c3; v3.w*=c3;
    }
    a0.x += v0.x; a0.y += v0.y; a0.z += v0.z; a0.w += v0.w;
    a1.x += v1.x; a1.y += v1.y; a1.z += v1.z; a1.w += v1.w;
    a2.x += v2.x; a2.y += v2.y; a2.z += v2.z; a2.w += v2.w;
    a3.x += v3.x; a3.y += v3.y; a3.z += v3.z; a3.w += v3.w;
  }
  for (; e < r1; e++){
    int s0 = col[e];
    float4 v0 = ((const float4*)(hs + (size_t)s0*128))[lane];
    if (SC){ float c0 = scale[s0]; v0.x*=c0; v0.y*=c0; v0.z*=c0; v0.w*=c0; }
    a0.x += v0.x; a0.y += v0.y; a0.z += v0.z; a0.w += v0.w;
  }
  float idst = inv_dst[node];
  float rx = ((a0.x + a1.x) + (a2.x + a3.x)) * idst;
  float ry = ((a0.y + a1.y) + (a2.y + a3.y)) * idst;
  float rz = ((a0.z + a1.z) + (a2.z + a3.z)) * idst;
  float rw = ((a0.w + a1.w) + (a2.w + a3.w)) * idst;
  uint4 p;
  p.x = pack_split(rx); p.y = pack_split(ry);
  p.z = pack_split(rz); p.w = pack_split(rw);
  ((uint4*)(aggp + (size_t)node*128))[lane] = p;
}

// Split-bf16 MFMA GEMM on packed A; B staged per-kc slice (20.5 KB LDS ->
// ~6 blocks/CU vs 2 with full staging; same traffic, same MFMA order).
__global__ __launch_bounds__(256) void mfma_gemm_kernel(
    const unsigned* __restrict__ A,
    const __bf16* __restrict__ Whi, const __bf16* __restrict__ Wlo,
    const float* __restrict__ bias, const float* __restrict__ out_scale,
    float* __restrict__ out, int M){
  __shared__ __bf16 BhL[128*40];   // [n][k-slice 32 + pad 8]
  __shared__ __bf16 BlL[128*40];

  const int tid  = threadIdx.x;
  const int wv   = tid >> 6;
  const int lane = tid & 63;
  const int q    = lane >> 4;
  const int mn   = lane & 15;
  const int row0 = blockIdx.x*128 + wv*32;

  f32x4 acc[2][8];
  #pragma unroll
  for (int mt = 0; mt < 2; mt++)
    #pragma unroll
    for (int nt = 0; nt < 8; nt++)
      acc[mt][nt] = (f32x4){0.f,0.f,0.f,0.f};

  #pragma unroll
  for (int kc = 0; kc < 4; kc++){
    __syncthreads();   // protect previous slice's reads
    for (int i = tid; i < 128*4; i += 256){   // 128 rows x 4 chunks of 8 bf16
      int n = i >> 2, c = (i & 3) << 3;
      *(bf16x8*)&BhL[n*40 + c] = *(const bf16x8*)(Whi + n*128 + kc*32 + c);
      *(bf16x8*)&BlL[n*40 + c] = *(const bf16x8*)(Wlo + n*128 + kc*32 + c);
    }
    __syncthreads();

    bf16x8 ah[2], al[2];
    #pragma unroll
    for (int mt = 0; mt < 2; mt++){
      const unsigned* ap = A + (size_t)(row0 + mt*16 + mn)*128 + kc*32 + q*8;
      uint4 x0 = *(const uint4*)ap;
      uint4 x1 = *(const uint4*)(ap + 4);
      unsigned v[8] = {x0.x, x0.y, x0.z, x0.w, x1.x, x1.y, x1.z, x1.w};
      #pragma unroll
      for (int j = 0; j < 8; j++){
        ah[mt][j] = bits_to_bf16((unsigned short)(v[j] >> 16));
        al[mt][j] = bits_to_bf16((unsigned short)(v[j] & 0xFFFFu));
      }
    }
    #pragma unroll
    for (int nt = 0; nt < 8; nt++){
      int boff = (nt*16 + mn)*40 + q*8;
      bf16x8 bh = *(const bf16x8*)&BhL[boff];
      bf16x8 bl = *(const bf16x8*)&BlL[boff];
      #pragma unroll
      for (int mt = 0; mt < 2; mt++){
        acc[mt][nt] = __builtin_amdgcn_mfma_f32_16x16x32_bf16(al[mt], bh, acc[mt][nt], 0, 0, 0);
        acc[mt][nt] = __builtin_amdgcn_mfma_f32_16x16x32_bf16(ah[mt], bl, acc[mt][nt], 0, 0, 0);
        acc[mt][nt] = __builtin_amdgcn_mfma_f32_16x16x32_bf16(ah[mt], bh, acc[mt][nt], 0, 0, 0);
      }
    }
  }

  #pragma unroll
  for (int mt = 0; mt < 2; mt++){
    #pragma unroll
    for (int r = 0; r < 4; r++){
      int gm = row0 + mt*16 + q*4 + r;
      if (gm < M){
        float osc = out_scale ? out_scale[gm] : 1.f;
        #pragma unroll
        for (int nt = 0; nt < 8; nt++){
          float v = acc[mt][nt][r] + bias[nt*16 + mn];
          v = fmaxf(v, 0.f) * osc;
          out[(size_t)gm*128 + nt*16 + mn] = v;
        }
      }
    }
  }
}

// Fused head: avg-pool (8 graphs/block) + MLP 128->512->256->1, all in LDS.
__global__ __launch_bounds__(256) void head_kernel(
    const float* __restrict__ h, const int* __restrict__ gid,
    const float* __restrict__ Wm0, const float* __restrict__ bm0,
    const float* __restrict__ Wm1, const float* __restrict__ bm1,
    const float* __restrict__ Wm2, const float* __restrict__ bm2,
    float* __restrict__ out, int N, int G){
  __shared__ float embL[8][128];
  __shared__ float x1L[8][512];
  __shared__ float x2L[8][256];

  const int t = threadIdx.x;
  const int wave = t >> 6, lane = t & 63;
  const int g0 = blockIdx.x * 8;

  for (int gg = 0; gg < 2; gg++){
    int gl = wave*2 + gg;
    int g = g0 + gl;
    float ax = 0.f, ay = 0.f;
    int start = 0, end = 0;
    if (g < G){
      int lo = 0, hi = N;
      while (lo < hi){ int mid = (lo + hi) >> 1; if (gid[mid] < g) lo = mid + 1; else hi = mid; }
      start = lo;
      hi = N;
      while (lo < hi){ int mid = (lo + hi) >> 1; if (gid[mid] <= g) lo = mid + 1; else hi = mid; }
      end = lo;
      for (int n = start; n < end; n++){
        float2 v = ((const float2*)(h + (size_t)n*128))[lane];
        ax += v.x; ay += v.y;
      }
    }
    int c = end - start; if (c < 1) c = 1;
    float invc = 1.0f / (float)c;
    embL[gl][2*lane]   = ax * invc;
    embL[gl][2*lane+1] = ay * invc;
  }
  __syncthreads();

  {
    float acc[8][2];
    #pragma unroll
    for (int g = 0; g < 8; g++){ acc[g][0] = 0.f; acc[g][1] = 0.f; }
    for (int k = 0; k < 128; k++){
      float w0 = Wm0[(size_t)k*512 + t];
      float w1 = Wm0[(size_t)k*512 + t + 256];
      #pragma unroll
      for (int g = 0; g < 8; g++){
        float e = embL[g][k];
        acc[g][0] = fmaf(e, w0, acc[g][0]);
        acc[g][1] = fmaf(e, w1, acc[g][1]);
      }
    }
    float b0v = bm0[t], b1v = bm0[t + 256];
    #pragma unroll
    for (int g = 0; g < 8; g++){
      x1L[g][t]       = fmaxf(acc[g][0] + b0v, 0.f);
      x1L[g][t + 256] = fmaxf(acc[g][1] + b1v, 0.f);
    }
  }
  __syncthreads();

  {
    float acc[8];
    #pragma unroll
    for (int g = 0; g < 8; g++) acc[g] = 0.f;
    for (int k = 0; k < 512; k++){
      float w = Wm1[(size_t)k*256 + t];
      #pragma unroll
      for (int g = 0; g < 8; g++)
        acc[g] = fmaf(x1L[g][k], w, acc[g]);
    }
    float bv = bm1[t];
    #pragma unroll
    for (int g = 0; g < 8; g++)
      x2L[g][t] = fmaxf(acc[g] + bv, 0.f);
  }
  __syncthreads();

  {
    int g = t >> 5;
    int c = t & 31;
    float s = 0.f;
    for (int i = c; i < 256; i += 32)
      s = fmaf(x2L[g][i], Wm2[i], s);
    for (int off = 16; off > 0; off >>= 1) s += __shfl_down(s, off, 32);
    if (c == 0 && (g0 + g) < G) out[g0 + g] = s + bm2[0];
  }
}

extern "C" void kernel_launch(void* const* d_in, const int* in_sizes, int n_in,
                              void* d_out, int out_size, void* d_ws, size_t ws_size,
                              hipStream_t stream){
  const float* feats = (const float*)d_in[0];
  const int*   src   = (const int*)d_in[1];
  const int*   dst   = (const int*)d_in[2];
  const int*   gid   = (const int*)d_in[3];
  const float* W0 = (const float*)d_in[4];   const float* b0 = (const float*)d_in[5];
  const float* W1 = (const float*)d_in[6];   const float* b1 = (const float*)d_in[7];
  const float* W2 = (const float*)d_in[8];   const float* b2 = (const float*)d_in[9];
  const float* Wm0 = (const float*)d_in[10]; const float* bm0 = (const float*)d_in[11];
  const float* Wm1 = (const float*)d_in[12]; const float* bm1 = (const float*)d_in[13];
  const float* Wm2 = (const float*)d_in[14]; const float* bm2 = (const float*)d_in[15];
  float* out = (float*)d_out;

  const int E   = in_sizes[1];
  const int N   = in_sizes[3];
  const int G   = out_size;
  const int NB  = ceil_div(N, 128);
  const int chunk = ceil_div(E, B1);
  const int strideB = (chunk + 3) & ~3;

  char* ws = (char*)d_ws;
  size_t off = 0;
  auto carve = [&](size_t bytes) -> char* {
    off = (off + 255) & ~(size_t)255;
    char* p = ws + off; off += bytes; return p;
  };
  float* inv_src = (float*)carve((size_t)N*4);
  float* inv_dst = (float*)carve((size_t)N*4);
  int* row_ptr = (int*)carve((size_t)(N+1)*4);
  int* col     = (int*)carve((size_t)E*4);
  __bf16* Wsp = (__bf16*)carve(6*128*128*2);   // hi0,lo0,hi1,lo1,hi2,lo2
  float* hs  = (float*)carve((size_t)N*128*4);
  unsigned* aggp = (unsigned*)carve((size_t)N*128*4);

  // CSR-build temporaries alias aggp (dead until first csr_agg writes it).
  unsigned* T = (unsigned*)aggp;
  unsigned* cntA   = T;
  unsigned* cntB   = cntA + (size_t)B1*NB;
  unsigned* totals = cntB + (size_t)B1*NB;
  unsigned* baseA  = totals + 2*(size_t)NB;
  unsigned* baseB  = baseA + (NB+1);
  unsigned* stagedA = baseB + (NB+1);
  unsigned char* stagedB = (unsigned char*)(stagedA + (size_t)B1*chunk);

  scatter_count_kernel<<<B1 + WPREP_BLOCKS, 256, 0, stream>>>(
      src, dst, cntA, cntB, stagedA, stagedB, W0, W1, W2, Wsp, E, NB);
  totals_kernel<<<dim3(ceil_div(NB,256), 2), 256, 0, stream>>>(cntA, cntB, totals, NB, E);
  scan_base_kernel<<<1, NBMAX, 0, stream>>>(totals, baseA, baseB, NB, E);
  csr_finalize_kernel<<<NB, 256, 0, stream>>>(stagedA, stagedB, cntA, cntB, baseA,
                                              row_ptr, inv_dst, inv_src, col, N, E, NB);

  const int agg_blocks = ceil_div(N*32, 256);
  const int ggrid = ceil_div(N, 128);
  __bf16 *Whi0 = Wsp,            *Wlo0 = Wsp + 16384;
  __bf16 *Whi1 = Wsp + 2*16384,  *Wlo1 = Wsp + 3*16384;
  __bf16 *Whi2 = Wsp + 4*16384,  *Wlo2 = Wsp + 5*16384;
  // layer 0
  csr_agg_kernel<true><<<agg_blocks, 256, 0, stream>>>(row_ptr, col, feats, inv_src, inv_dst, aggp, N);
  mfma_gemm_kernel<<<ggrid, 256, 0, stream>>>(aggp, Whi0, Wlo0, b0, inv_src, hs, N);
  // layer 1
  csr_agg_kernel<false><<<agg_blocks, 256, 0, stream>>>(row_ptr, col, hs, nullptr, inv_dst, aggp, N);
  mfma_gemm_kernel<<<ggrid, 256, 0, stream>>>(aggp, Whi1, Wlo1, b1, inv_src, hs, N);
  // layer 2 (no out_scale)
  csr_agg_kernel<false><<<agg_blocks, 256, 0, stream>>>(row_ptr, col, hs, nullptr, inv_dst, aggp, N);
  mfma_gemm_kernel<<<ggrid, 256, 0, stream>>>(aggp, Whi2, Wlo2, b2, nullptr, hs, N);
  // fused pool + MLP head
  head_kernel<<<ceil_div(G,8), 256, 0, stream>>>(hs, gid, Wm0, bm0, Wm1, bm1, Wm2, bm2, out, N, G);
}